// Round 15
// baseline (9160.017 us; speedup 1.0000x reference)
//
#include <hip/hip_runtime.h>

// ---------------------------------------------------------------------------
// OmniAnomaly forward, round 15: r14 (XCD-local slab groups, 8.98ms) with
// deeper weight-load pipelining: unroll 8 on K=1024 weight loops (24 loads
// in flight/wave vs 12) + launch_bounds(512,2) to allow 256 VGPRs/wave.
// Weight stream was MLP-limited at 1.25 TB/s; target ~2-2.5 TB/s.
// Everything else identical to r14 (proven).
// B=256, W=128, IN=128, H=1024, Z=128, D=1024, OUT=128, K=3 flows
// ---------------------------------------------------------------------------

typedef __bf16 bf16;
typedef __bf16 bf16x8 __attribute__((ext_vector_type(8)));
typedef float  f32x4  __attribute__((ext_vector_type(4)));
typedef unsigned u32;

static constexpr int CB   = 256;
static constexpr int CW   = 128;
static constexpr int CIN  = 128;
static constexpr int CH   = 1024;
static constexpr int CZ   = 128;
static constexpr int CD   = 1024;
static constexpr int COUT = 128;

static constexpr int APITCH     = 1160;                      // 1152 + 8 pad
static constexpr int ABUF_BYTES = 16 * APITCH * 2;           // 37120
static constexpr int REDN       = 8 * 16 * 17;
static constexpr int RED2_BYTES = 2 * REDN * 4;              // 17408
static constexpr int FLOW_BYTES = (2 * CZ + 2 * 2 * CZ) * 4; // 3072
static constexpr int SMEM_BYTES = ABUF_BYTES + RED2_BYTES + FLOW_BYTES; // 57600

// s_getreg imm: ID=20 (HW_REG_XCC_ID), offset 0, width 32 -> 20 | (31<<11)
static constexpr int XCC_GETREG = 20 | (31 << 11);

#define DEV static __device__ __forceinline__

DEV float sigmoidf_(float x) { return 1.0f / (1.0f + expf(-x)); }
DEV float softplusf_(float x) { return x > 20.0f ? x : log1pf(expf(x)); }
DEV bf16x8 ldfrag(const bf16* p) { return *reinterpret_cast<const bf16x8*>(p); }

#define MFMA(a, b, c) __builtin_amdgcn_mfma_f32_16x16x32_bf16((a), (b), (c), 0, 0, 0)

// ---- mode-dependent coherent accesses ----
template <bool FAST> DEV bf16x8 ldx16(const bf16* p) {
    bf16x8 v;
    if constexpr (FAST)
        asm volatile("global_load_dwordx4 %0, %1, off sc0\n\ts_waitcnt vmcnt(0)"
                     : "=v"(v) : "v"(p) : "memory");
    else
        asm volatile("global_load_dwordx4 %0, %1, off sc0 sc1\n\ts_waitcnt vmcnt(0)"
                     : "=v"(v) : "v"(p) : "memory");
    return v;
}
template <bool FAST> DEV u32 ldx4(const void* p) {
    u32 v;
    if constexpr (FAST)
        asm volatile("global_load_dword %0, %1, off sc0\n\ts_waitcnt vmcnt(0)"
                     : "=v"(v) : "v"(p) : "memory");
    else
        asm volatile("global_load_dword %0, %1, off sc0 sc1\n\ts_waitcnt vmcnt(0)"
                     : "=v"(v) : "v"(p) : "memory");
    return v;
}
template <bool FAST> DEV void stx4(void* p, u32 v) {
    if constexpr (FAST)
        asm volatile("global_store_dword %0, %1, off sc0" :: "v"(p), "v"(v) : "memory");
    else
        asm volatile("global_store_dword %0, %1, off sc0 sc1" :: "v"(p), "v"(v) : "memory");
}
DEV u32 pk2(float a, float b) {
    union { bf16 h[2]; u32 u; } r;
    r.h[0] = (bf16)a; r.h[1] = (bf16)b;
    return r.u;
}

struct Prm {
    const float *eps_q, *eps_p;
    const float *bih_q, *bhh_q, *bd_q, *bmu_q, *bsig_q;
    const float *Wp, *bp, *up, *Wlg, *blg;
    const float *bih_p, *bhh_p, *bd_p, *bmu_p, *bsig_p;
    const bf16 *x_b, *Wih_qb, *Whh_qb, *Wd_qb, *Wmu_qb, *Wsg_qb;
    const bf16 *Wih_pb, *Whh_pb, *Wd_pb, *Wmu_pb, *Wsg_pb;
    float *e_f0, *e_f1, *d_f0, *d_f1;
    bf16 *e_b0, *e_b1, *d_b0, *d_b1;
    float *ztmp_f;
    bf16 *dvec_b, *ddvec_b;
    bf16 *zflow;    // [2][CB][CZ]
    bf16 *ztlg;     // [2][CB][CZ]
    u32 *qbar, *pbar;
    u32 *zbar, *pdone;
    u32 *xcc, *cnt;
    float *out_o, *out_mu, *out_lv;
};

// 8-WG group barrier (flags agent-scope -> correct on any placement).
DEV void gbar_g(u32* flg, int slice, u32 k)
{
    asm volatile("s_waitcnt vmcnt(0)" ::: "memory");
    __syncthreads();
    if (threadIdx.x == 0)
        __hip_atomic_store(&flg[slice * 16], k, __ATOMIC_RELAXED, __HIP_MEMORY_SCOPE_AGENT);
    if (threadIdx.x < 8) {
        while (__hip_atomic_load(&flg[threadIdx.x * 16], __ATOMIC_RELAXED,
                                 __HIP_MEMORY_SCOPE_AGENT) < k)
            __builtin_amdgcn_s_sleep(1);
    }
    __syncthreads();
}

// ---------------------------------------------------------------------------
__global__ void k_cvt(const float* __restrict__ src, bf16* __restrict__ dst, int n)
{
    int i = (blockIdx.x * blockDim.x + threadIdx.x) * 4;
    if (i < n) {
        float4 v = *reinterpret_cast<const float4*>(src + i);
        *reinterpret_cast<u32*>(dst + i)     = pk2(v.x, v.y);
        *reinterpret_cast<u32*>(dst + i + 2) = pk2(v.z, v.w);
    }
}

// ---------------------------------------------------------------------------
template <bool FAST, bool HC>
DEV void stage_act(bf16* abuf, int tid, int r0,
                   const bf16* head, long hs, int K1,
                   const bf16* body, long bs)
{
    const int CHN = (K1 + CH) >> 3;
    const int TOT = 16 * CHN;
    for (int idx = tid; idx < TOT; idx += 512) {
        const int row = idx / CHN;
        const int k = (idx - row * CHN) * 8;
        bf16x8 v;
        if (k < K1) {
            const bf16* s = head + (long)(r0 + row) * hs + k;
            v = HC ? ldfrag(s) : ldx16<FAST>(s);
        } else {
            v = ldx16<FAST>(body + (long)(r0 + row) * bs + (k - K1));
        }
        *reinterpret_cast<bf16x8*>(abuf + (long)row * APITCH + k) = v;
    }
    __syncthreads();
}

// ---------------------------------------------------------------------------
// GRU compute: unroll 8 on the K=1024 loop -> ~24 weight loads in flight.
// ---------------------------------------------------------------------------
template <bool FAST>
DEV void gru_compute(const bf16* abuf, int r0, int n0, int lane, int wave,
                     const bf16* __restrict__ Wih, const bf16* __restrict__ Whh,
                     const float* __restrict__ bih, const float* __restrict__ bhh,
                     const float* __restrict__ Efin,
                     float* __restrict__ Efo, bf16* __restrict__ Ebo)
{
    const int lr = lane & 15, lkE = (lane >> 4) * 8;
    const int c = n0 + wave * 16 + lr;
    const bf16* arow = abuf + (long)lr * APITCH;

    f32x4 acc[4] = {};
#pragma unroll 4
    for (int k = 0; k < CIN; k += 32) {
        bf16x8 a = *reinterpret_cast<const bf16x8*>(arow + k + lkE);
#pragma unroll
        for (int g = 0; g < 3; ++g) {
            bf16x8 b = ldfrag(Wih + ((long)g * CH + c) * CIN + k + lkE);
            const int grp = (g == 2) ? 2 : g;
            acc[grp] = MFMA(a, b, acc[grp]);
        }
    }
#pragma unroll 8
    for (int k = 0; k < CH; k += 32) {
        bf16x8 a = *reinterpret_cast<const bf16x8*>(arow + CIN + k + lkE);
#pragma unroll
        for (int g = 0; g < 3; ++g) {
            bf16x8 b = ldfrag(Whh + ((long)g * CH + c) * CH + k + lkE);
            const int grp = (g == 2) ? 3 : g;
            acc[grp] = MFMA(a, b, acc[grp]);
        }
    }

    const float b0r = bih[c] + bhh[c];
    const float b0z = bih[CH + c] + bhh[CH + c];
    const float bin = bih[2 * CH + c];
    const float bhn = bhh[2 * CH + c];
    const int rbase = r0 + (lane >> 4) * 4;
#pragma unroll
    for (int i = 0; i < 4; ++i) {
        const int row = rbase + i;
        float r = sigmoidf_(acc[0][i] + b0r);
        float u = sigmoidf_(acc[1][i] + b0z);
        float n = tanhf(acc[2][i] + bin + r * (acc[3][i] + bhn));
        float en = (1.0f - u) * n + u * Efin[(long)row * CH + c];
        Efo[(long)row * CH + c] = en;
        float vB = __shfl_xor(en, 1);
        if (!(lane & 1))
            stx4<FAST>(Ebo + (long)row * CH + c, pk2(en, vB));
    }
}

// ---------------------------------------------------------------------------
template <bool FAST>
DEV void lin_compute(const bf16* abuf, int r0, int n0, int lane, int wave, int Ktot,
                     const bf16* __restrict__ W,
                     const float* __restrict__ bias, bf16* __restrict__ Out)
{
    const int lr = lane & 15, lkE = (lane >> 4) * 8;
    const int c = n0 + wave * 16 + lr;
    const bf16* arow = abuf + (long)lr * APITCH;
    const bf16* wrow = W + (long)c * Ktot;

    f32x4 acc = {};
#pragma unroll 8
    for (int k = 0; k < CH; k += 32) {
        bf16x8 a = *reinterpret_cast<const bf16x8*>(arow + (Ktot - CH) + k + lkE);
        bf16x8 b = ldfrag(wrow + (Ktot - CH) + k + lkE);
        acc = MFMA(a, b, acc);
    }
    if (Ktot > CH) {
#pragma unroll 4
        for (int k = 0; k < CZ; k += 32) {
            bf16x8 a = *reinterpret_cast<const bf16x8*>(arow + k + lkE);
            bf16x8 b = ldfrag(wrow + k + lkE);
            acc = MFMA(a, b, acc);
        }
    }

    const float bb = bias[c];
    const int rbase = r0 + (lane >> 4) * 4;
#pragma unroll
    for (int i = 0; i < 4; ++i) {
        float v = acc[i] + bb;
        float vB = __shfl_xor(v, 1);
        if (!(lane & 1))
            stx4<FAST>(Out + (long)(rbase + i) * CD + c, pk2(v, vB));
    }
}

// ---------------------------------------------------------------------------
template <bool FAST, int MODE>
DEV void phase_tail2(const Prm& p, int t, int slab, int slice, int tid,
                     int lane, int wave, float* Ra, float* Rs,
                     const bf16* __restrict__ A,
                     const bf16* __restrict__ Wa, const bf16* __restrict__ Wb,
                     const float* __restrict__ ba, const float* __restrict__ bb)
{
    const int lr = lane & 15, lkE = (lane >> 4) * 8;
    const int mb = slab * 16;
    const int nb = slice * 16;
    f32x4 am = {}, as = {};
    const int k0 = wave * 128;
#pragma unroll
    for (int kk = 0; kk < 128; kk += 32) {
        const int k = k0 + kk;
        bf16x8 a  = ldx16<FAST>(A + (long)(mb + lr) * CD + k + lkE);
        bf16x8 bm = ldfrag(Wa + (long)(nb + lr) * CD + k + lkE);
        bf16x8 bs = ldfrag(Wb + (long)(nb + lr) * CD + k + lkE);
        am = MFMA(a, bm, am);
        as = MFMA(a, bs, as);
    }
    __syncthreads();
#pragma unroll
    for (int i = 0; i < 4; ++i) {
        Ra[(wave * 16 + (lane >> 4) * 4 + i) * 17 + lr] = am[i];
        Rs[(wave * 16 + (lane >> 4) * 4 + i) * 17 + lr] = as[i];
    }
    __syncthreads();
    if (tid < 256) {
        const int trow = tid >> 4, tcol = tid & 15;
        float vm = 0.f, vs = 0.f;
#pragma unroll
        for (int w = 0; w < 8; ++w) {
            vm += Ra[(w * 16 + trow) * 17 + tcol];
            vs += Rs[(w * 16 + trow) * 17 + tcol];
        }
        const int row = mb + trow, col = nb + tcol;
        if constexpr (MODE == 0) {
            float mu = vm + ba[col];
            float lv = softplusf_(vs + bb[col]);
            float e  = p.eps_q[(long)row * CW * CZ + (long)t * CZ + col];
            float z  = mu + expf(0.5f * lv) * e;
            p.out_mu[(long)row * CW * CZ + (long)t * CZ + col] = mu;
            p.out_lv[(long)row * CW * CZ + (long)t * CZ + col] = lv;
            stx4<FAST>(p.ztmp_f + (long)row * CZ + col, __float_as_uint(z));
        } else {
            float m  = vm + ba[col];
            float sg = softplusf_(vs + bb[col]);
            float e  = p.eps_p[(long)row * CW * COUT + (long)t * COUT + col];
            p.out_o[(long)row * CW * COUT + (long)t * COUT + col] = m + sg * e;
        }
    }
}

// ---------------------------------------------------------------------------
template <bool FAST>
DEV void phase_flows2(const Prm& p, int rowbase, int tid, int t, float* zl, float* ps)
{
    const int rg = tid >> 8;
    const int sub = tid & 255;
    const int c = sub & 127, half = sub >> 7;
    const int row = rowbase + rg;
    float* zrow = zl + rg * CZ;
    float* pall = ps + rg * 2 * CZ;

    if (half == 0)
        zrow[c] = __uint_as_float(ldx4<FAST>(p.ztmp_f + (long)row * CZ + c));
    __syncthreads();

#pragma unroll 1
    for (int kf = 0; kf < 3; ++kf) {
        const float* wr = p.Wp + ((long)kf * CZ + c) * CZ + half * 64;
        const float* zh = zrow + half * 64;
        float s = 0.f;
#pragma unroll
        for (int j = 0; j < 64; j += 4) {
            float4 w = *reinterpret_cast<const float4*>(wr + j);
            s += zh[j] * w.x + zh[j + 1] * w.y + zh[j + 2] * w.z + zh[j + 3] * w.w;
        }
        pall[half * CZ + c] = s;
        __syncthreads();
        if (half == 0) {
            float sf = pall[c] + pall[CZ + c] + p.bp[kf * CZ + c];
            zrow[c] += p.up[kf] * tanhf(sf);
        }
        __syncthreads();
    }
    {
        const float* wr = p.Wlg + (long)c * CZ + half * 64;
        const float* zh = zrow + half * 64;
        float s = 0.f;
#pragma unroll
        for (int j = 0; j < 64; j += 4) {
            float4 w = *reinterpret_cast<const float4*>(wr + j);
            s += zh[j] * w.x + zh[j + 1] * w.y + zh[j + 2] * w.z + zh[j + 3] * w.w;
        }
        pall[half * CZ + c] = s;
        __syncthreads();
        if (half == 0) {
            float zt = pall[c] + pall[CZ + c] + p.blg[c];
            float ztB = __shfl_xor(zt, 1);
            if (!(c & 1)) {
                stx4<FAST>(p.ztlg + ((size_t)(t & 1) * CB + row) * CZ + c, pk2(zt, ztB));
                stx4<FAST>(p.zflow + ((size_t)((t + 1) & 1) * CB + row) * CZ + c,
                           pk2(zrow[c], zrow[c + 1]));
            }
        }
    }
}

// ---------------------------------------------------------------------------
template <bool FAST>
DEV void run_q(const Prm& p, int slab, int slice, int tid,
               bf16* abuf, float* Ra, float* Rs, float* ZLp, float* PSp)
{
    const int lane = tid & 63, wave = tid >> 6;
    const int r0 = slab * 16, n0 = slice * 128;
    u32* qb = p.qbar + slab * 8 * 16;
    u32 bk = 0;
#pragma unroll 1
    for (int t = 0; t < CW; ++t) {
        const int bi = t & 1;
        const bf16*  eb_i = bi ? p.e_b1 : p.e_b0;
        const float* ef_i = bi ? p.e_f1 : p.e_f0;
        bf16*  eb_o = bi ? p.e_b0 : p.e_b1;
        float* ef_o = bi ? p.e_f0 : p.e_f1;

        stage_act<FAST, true>(abuf, tid, r0, p.x_b + (long)t * CIN, (long)CW * CIN,
                              CIN, eb_i, CH);
        gru_compute<FAST>(abuf, r0, n0, lane, wave, p.Wih_qb, p.Whh_qb,
                          p.bih_q, p.bhh_q, ef_i, ef_o, eb_o);
        gbar_g(qb, slice, ++bk);
        stage_act<FAST, false>(abuf, tid, r0, p.zflow + (size_t)bi * CB * CZ,
                               CZ, CZ, eb_o, CH);
        lin_compute<FAST>(abuf, r0, n0, lane, wave, CZ + CH, p.Wd_qb, p.bd_q, p.dvec_b);
        gbar_g(qb, slice, ++bk);
        phase_tail2<FAST, 0>(p, t, slab, slice, tid, lane, wave, Ra, Rs,
                             p.dvec_b, p.Wmu_qb, p.Wsg_qb, p.bmu_q, p.bsig_q);
        gbar_g(qb, slice, ++bk);
        if (t >= 2) {
            if (tid == 0) {
                while ((int)__hip_atomic_load(&p.pdone[slab * 16], __ATOMIC_RELAXED,
                                              __HIP_MEMORY_SCOPE_AGENT) < t - 1)
                    __builtin_amdgcn_s_sleep(2);
            }
            __syncthreads();
        }
        phase_flows2<FAST>(p, slab * 16 + slice * 2, tid, t, ZLp, PSp);
        gbar_g(qb, slice, ++bk);
        if (slice == 0 && tid == 0)
            __hip_atomic_store(&p.zbar[slab * 16], (u32)(t + 1),
                               __ATOMIC_RELAXED, __HIP_MEMORY_SCOPE_AGENT);
    }
}

template <bool FAST>
DEV void run_p(const Prm& p, int slab, int slice, int tid,
               bf16* abuf, float* Ra, float* Rs)
{
    const int lane = tid & 63, wave = tid >> 6;
    const int r0 = slab * 16, n0 = slice * 128;
    u32* pb = p.pbar + slab * 8 * 16;
    u32 bk = 0;
#pragma unroll 1
    for (int t = 0; t < CW; ++t) {
        if (tid == 0) {
            while (__hip_atomic_load(&p.zbar[slab * 16], __ATOMIC_RELAXED,
                                     __HIP_MEMORY_SCOPE_AGENT) < (u32)(t + 1))
                __builtin_amdgcn_s_sleep(2);
        }
        __syncthreads();

        const int bi = t & 1;
        const bf16*  db_i = bi ? p.d_b1 : p.d_b0;
        const float* df_i = bi ? p.d_f1 : p.d_f0;
        bf16*  db_o = bi ? p.d_b0 : p.d_b1;
        float* df_o = bi ? p.d_f0 : p.d_f1;

        stage_act<FAST, false>(abuf, tid, r0, p.ztlg + (size_t)bi * CB * CZ,
                               CZ, CZ, db_i, CH);
        gru_compute<FAST>(abuf, r0, n0, lane, wave, p.Wih_pb, p.Whh_pb,
                          p.bih_p, p.bhh_p, df_i, df_o, db_o);
        gbar_g(pb, slice, ++bk);
        if (slice == 0 && tid == 0)
            __hip_atomic_store(&p.pdone[slab * 16], (u32)(t + 1),
                               __ATOMIC_RELAXED, __HIP_MEMORY_SCOPE_AGENT);
        stage_act<FAST, false>(abuf, tid, r0, nullptr, 0, 0, db_o, CH);
        lin_compute<FAST>(abuf, r0, n0, lane, wave, CH, p.Wd_pb, p.bd_p, p.ddvec_b);
        gbar_g(pb, slice, ++bk);
        phase_tail2<FAST, 1>(p, t, slab, slice, tid, lane, wave, Ra, Rs,
                             p.ddvec_b, p.Wmu_pb, p.Wsg_pb, p.bmu_p, p.bsig_p);
    }
}

// ---------------------------------------------------------------------------
__launch_bounds__(512, 2)
__global__ void mega(Prm p)
{
    extern __shared__ char smem[];
    bf16*  abuf = (bf16*)smem;
    float* Ra   = (float*)(smem + ABUF_BYTES);
    float* Rs   = Ra + REDN;
    float* ZLp  = (float*)(smem + ABUF_BYTES + RED2_BYTES);
    float* PSp  = ZLp + 2 * CZ;
    __shared__ int s_fast;

    const int wg = blockIdx.x, tid = threadIdx.x;
    const int gid = wg & 7, m = wg >> 3;
    const bool isQ = m < 16;
    const int slab = gid * 2 + ((m & 15) >> 3);
    const int slice = m & 7;

    const u32 myx = (u32)__builtin_amdgcn_s_getreg(XCC_GETREG);
    if (tid == 0) {
        __hip_atomic_store(&p.xcc[wg * 16], myx, __ATOMIC_RELAXED, __HIP_MEMORY_SCOPE_AGENT);
        __hip_atomic_fetch_add(p.cnt, 1u, __ATOMIC_RELAXED, __HIP_MEMORY_SCOPE_AGENT);
        while (__hip_atomic_load(p.cnt, __ATOMIC_RELAXED, __HIP_MEMORY_SCOPE_AGENT) < 256u)
            __builtin_amdgcn_s_sleep(2);
    }
    __syncthreads();
    if (tid < 64) {
        bool eq = true;
        if (tid < 32) {
            u32 o = __hip_atomic_load(&p.xcc[(gid + 8 * tid) * 16],
                                      __ATOMIC_RELAXED, __HIP_MEMORY_SCOPE_AGENT);
            eq = (o == myx);
        }
        unsigned long long b = __ballot(eq);
        if (tid == 0) s_fast = (b == ~0ull) ? 1 : 0;
    }
    __syncthreads();
    const bool fast = (s_fast != 0);

    if (isQ) {
        if (fast) run_q<true>(p, slab, slice, tid, abuf, Ra, Rs, ZLp, PSp);
        else      run_q<false>(p, slab, slice, tid, abuf, Ra, Rs, ZLp, PSp);
    } else {
        if (fast) run_p<true>(p, slab, slice, tid, abuf, Ra, Rs);
        else      run_p<false>(p, slab, slice, tid, abuf, Ra, Rs);
    }
}

// ---------------------------------------------------------------------------
// Host driver
// ---------------------------------------------------------------------------
extern "C" void kernel_launch(void* const* d_in, const int* in_sizes, int n_in,
                              void* d_out, int out_size, void* d_ws, size_t ws_size,
                              hipStream_t stream)
{
    Prm p;
    const float* x      = (const float*)d_in[0];
    p.eps_q  = (const float*)d_in[1];
    p.eps_p  = (const float*)d_in[2];
    const float* Wih_q  = (const float*)d_in[3];
    const float* Whh_q  = (const float*)d_in[4];
    p.bih_q  = (const float*)d_in[5];
    p.bhh_q  = (const float*)d_in[6];
    const float* Wd_q   = (const float*)d_in[7];
    p.bd_q   = (const float*)d_in[8];
    const float* Wmu_q  = (const float*)d_in[9];
    p.bmu_q  = (const float*)d_in[10];
    const float* Wsig_q = (const float*)d_in[11];
    p.bsig_q = (const float*)d_in[12];
    p.Wp     = (const float*)d_in[13];
    p.bp     = (const float*)d_in[14];
    p.up     = (const float*)d_in[15];
    p.Wlg    = (const float*)d_in[16];
    p.blg    = (const float*)d_in[17];
    const float* Wih_p  = (const float*)d_in[18];
    const float* Whh_p  = (const float*)d_in[19];
    p.bih_p  = (const float*)d_in[20];
    p.bhh_p  = (const float*)d_in[21];
    const float* Wd_p   = (const float*)d_in[22];
    p.bd_p   = (const float*)d_in[23];
    const float* Wmu_p  = (const float*)d_in[24];
    p.bmu_p  = (const float*)d_in[25];
    const float* Wsig_p = (const float*)d_in[26];
    p.bsig_p = (const float*)d_in[27];

    p.out_o  = (float*)d_out;
    p.out_mu = p.out_o + (size_t)CB * CW * COUT;
    p.out_lv = p.out_mu + (size_t)CB * CW * CZ;

    char* wp_ = (char*)d_ws;
    auto carve = [&](size_t bytes) -> void* {
        void* q = (void*)wp_;
        wp_ += (bytes + 255) & ~(size_t)255;
        return q;
    };
    p.e_f0 = (float*)carve((size_t)CB * CH * 4);
    p.e_f1 = (float*)carve((size_t)CB * CH * 4);
    p.d_f0 = (float*)carve((size_t)CB * CH * 4);
    p.d_f1 = (float*)carve((size_t)CB * CH * 4);
    p.e_b0 = (bf16*)carve((size_t)CB * CH * 2);
    p.e_b1 = (bf16*)carve((size_t)CB * CH * 2);
    p.d_b0 = (bf16*)carve((size_t)CB * CH * 2);
    p.d_b1 = (bf16*)carve((size_t)CB * CH * 2);
    p.ztmp_f  = (float*)carve((size_t)CB * CZ * 4);
    p.dvec_b  = (bf16*)carve((size_t)CB * CD * 2);
    p.ddvec_b = (bf16*)carve((size_t)CB * CD * 2);
    p.zflow   = (bf16*)carve((size_t)2 * CB * CZ * 2);
    p.ztlg    = (bf16*)carve((size_t)2 * CB * CZ * 2);
    p.qbar    = (u32*)carve((size_t)16 * 8 * 16 * 4);
    p.pbar    = (u32*)carve((size_t)16 * 8 * 16 * 4);
    p.zbar    = (u32*)carve((size_t)16 * 16 * 4);
    p.pdone   = (u32*)carve((size_t)16 * 16 * 4);
    p.xcc     = (u32*)carve((size_t)256 * 16 * 4);
    p.cnt     = (u32*)carve(256);
    bf16* x_b    = (bf16*)carve((size_t)CB * CW * CIN * 2);
    bf16* Wih_qb = (bf16*)carve((size_t)3 * CH * CIN * 2);
    bf16* Whh_qb = (bf16*)carve((size_t)3 * CH * CH * 2);
    bf16* Wd_qb  = (bf16*)carve((size_t)CD * (CZ + CH) * 2);
    bf16* Wmu_qb = (bf16*)carve((size_t)CZ * CD * 2);
    bf16* Wsg_qb = (bf16*)carve((size_t)CZ * CD * 2);
    bf16* Wih_pb = (bf16*)carve((size_t)3 * CH * CZ * 2);
    bf16* Whh_pb = (bf16*)carve((size_t)3 * CH * CH * 2);
    bf16* Wd_pb  = (bf16*)carve((size_t)CD * CH * 2);
    bf16* Wmu_pb = (bf16*)carve((size_t)COUT * CD * 2);
    bf16* Wsg_pb = (bf16*)carve((size_t)COUT * CD * 2);
    p.x_b = x_b;       p.Wih_qb = Wih_qb; p.Whh_qb = Whh_qb;
    p.Wd_qb = Wd_qb;   p.Wmu_qb = Wmu_qb; p.Wsg_qb = Wsg_qb;
    p.Wih_pb = Wih_pb; p.Whh_pb = Whh_pb; p.Wd_pb = Wd_pb;
    p.Wmu_pb = Wmu_pb; p.Wsg_pb = Wsg_pb;

    hipMemsetAsync(p.e_f0, 0, (size_t)CB * CH * 4, stream);
    hipMemsetAsync(p.d_f0, 0, (size_t)CB * CH * 4, stream);
    hipMemsetAsync(p.e_b0, 0, (size_t)CB * CH * 2, stream);
    hipMemsetAsync(p.d_b0, 0, (size_t)CB * CH * 2, stream);
    hipMemsetAsync(p.zflow, 0, (size_t)CB * CZ * 2, stream);
    hipMemsetAsync(p.qbar, 0, (size_t)16 * 8 * 16 * 4, stream);
    hipMemsetAsync(p.pbar, 0, (size_t)16 * 8 * 16 * 4, stream);
    hipMemsetAsync(p.zbar, 0, (size_t)16 * 16 * 4, stream);
    hipMemsetAsync(p.pdone, 0, (size_t)16 * 16 * 4, stream);
    hipMemsetAsync(p.xcc, 0, (size_t)256 * 16 * 4, stream);
    hipMemsetAsync(p.cnt, 0, 256, stream);

    auto cvt = [&](const float* s, bf16* d, size_t n) {
        k_cvt<<<dim3((unsigned)((n / 4 + 255) / 256)), dim3(256), 0, stream>>>(s, d, (int)n);
    };
    cvt(x,      x_b,    (size_t)CB * CW * CIN);
    cvt(Wih_q,  Wih_qb, (size_t)3 * CH * CIN);
    cvt(Whh_q,  Whh_qb, (size_t)3 * CH * CH);
    cvt(Wd_q,   Wd_qb,  (size_t)CD * (CZ + CH));
    cvt(Wmu_q,  Wmu_qb, (size_t)CZ * CD);
    cvt(Wsig_q, Wsg_qb, (size_t)CZ * CD);
    cvt(Wih_p,  Wih_pb, (size_t)3 * CH * CZ);
    cvt(Whh_p,  Whh_pb, (size_t)3 * CH * CH);
    cvt(Wd_p,   Wd_pb,  (size_t)CD * CH);
    cvt(Wmu_p,  Wmu_pb, (size_t)COUT * CD);
    cvt(Wsig_p, Wsg_pb, (size_t)COUT * CD);

    mega<<<dim3(256), dim3(512), SMEM_BYTES, stream>>>(p);
}

// Round 16
// 8708.887 us; speedup vs baseline: 1.0518x; 1.0518x over previous
//
#include <hip/hip_runtime.h>

// ---------------------------------------------------------------------------
// OmniAnomaly forward, round 16: Q/P XCD specialization.
// r14 structure (8.98ms proven), new role map: XCDs 0-3 run ONLY Qnet
// (4 slabs each), XCDs 4-7 ONLY Pnet. Per-XCD weight demand 19.5 -> ~10 MB/step
// (the measured bottleneck: 81 MB/step of L2-miss weight stream @1.25 TB/s).
// Only ztlg (Q->P latent, 64KB/step) crosses XCDs -> always sc0sc1 (r13 path).
// Everything else slab-group-local with sc0 fast path. Fallback: device scope.
// B=256, W=128, IN=128, H=1024, Z=128, D=1024, OUT=128, K=3 flows
// ---------------------------------------------------------------------------

typedef __bf16 bf16;
typedef __bf16 bf16x8 __attribute__((ext_vector_type(8)));
typedef float  f32x4  __attribute__((ext_vector_type(4)));
typedef unsigned u32;

static constexpr int CB   = 256;
static constexpr int CW   = 128;
static constexpr int CIN  = 128;
static constexpr int CH   = 1024;
static constexpr int CZ   = 128;
static constexpr int CD   = 1024;
static constexpr int COUT = 128;

static constexpr int APITCH     = 1160;                      // 1152 + 8 pad
static constexpr int ABUF_BYTES = 16 * APITCH * 2;           // 37120
static constexpr int REDN       = 8 * 16 * 17;
static constexpr int RED2_BYTES = 2 * REDN * 4;              // 17408
static constexpr int FLOW_BYTES = (2 * CZ + 2 * 2 * CZ) * 4; // 3072
static constexpr int SMEM_BYTES = ABUF_BYTES + RED2_BYTES + FLOW_BYTES; // 57600

// s_getreg imm: ID=20 (HW_REG_XCC_ID), offset 0, width 32 -> 20 | (31<<11)
static constexpr int XCC_GETREG = 20 | (31 << 11);

#define DEV static __device__ __forceinline__

DEV float sigmoidf_(float x) { return 1.0f / (1.0f + expf(-x)); }
DEV float softplusf_(float x) { return x > 20.0f ? x : log1pf(expf(x)); }
DEV bf16x8 ldfrag(const bf16* p) { return *reinterpret_cast<const bf16x8*>(p); }

#define MFMA(a, b, c) __builtin_amdgcn_mfma_f32_16x16x32_bf16((a), (b), (c), 0, 0, 0)

// ---- mode-dependent coherent accesses ----
template <bool FAST> DEV bf16x8 ldx16(const bf16* p) {
    bf16x8 v;
    if constexpr (FAST)
        asm volatile("global_load_dwordx4 %0, %1, off sc0\n\ts_waitcnt vmcnt(0)"
                     : "=v"(v) : "v"(p) : "memory");
    else
        asm volatile("global_load_dwordx4 %0, %1, off sc0 sc1\n\ts_waitcnt vmcnt(0)"
                     : "=v"(v) : "v"(p) : "memory");
    return v;
}
template <bool FAST> DEV u32 ldx4(const void* p) {
    u32 v;
    if constexpr (FAST)
        asm volatile("global_load_dword %0, %1, off sc0\n\ts_waitcnt vmcnt(0)"
                     : "=v"(v) : "v"(p) : "memory");
    else
        asm volatile("global_load_dword %0, %1, off sc0 sc1\n\ts_waitcnt vmcnt(0)"
                     : "=v"(v) : "v"(p) : "memory");
    return v;
}
template <bool FAST> DEV void stx4(void* p, u32 v) {
    if constexpr (FAST)
        asm volatile("global_store_dword %0, %1, off sc0" :: "v"(p), "v"(v) : "memory");
    else
        asm volatile("global_store_dword %0, %1, off sc0 sc1" :: "v"(p), "v"(v) : "memory");
}
DEV u32 pk2(float a, float b) {
    union { bf16 h[2]; u32 u; } r;
    r.h[0] = (bf16)a; r.h[1] = (bf16)b;
    return r.u;
}

struct Prm {
    const float *eps_q, *eps_p;
    const float *bih_q, *bhh_q, *bd_q, *bmu_q, *bsig_q;
    const float *Wp, *bp, *up, *Wlg, *blg;
    const float *bih_p, *bhh_p, *bd_p, *bmu_p, *bsig_p;
    const bf16 *x_b, *Wih_qb, *Whh_qb, *Wd_qb, *Wmu_qb, *Wsg_qb;
    const bf16 *Wih_pb, *Whh_pb, *Wd_pb, *Wmu_pb, *Wsg_pb;
    float *e_f0, *e_f1, *d_f0, *d_f1;
    bf16 *e_b0, *e_b1, *d_b0, *d_b1;
    float *ztmp_f;
    bf16 *dvec_b, *ddvec_b;
    bf16 *zflow;    // [2][CB][CZ]  (Q-internal)
    bf16 *ztlg;     // [2][CB][CZ]  (Q->P, ALWAYS device-scope sc0sc1)
    u32 *qbar, *pbar;
    u32 *zbar, *pdone;
    u32 *xcc, *cnt;
    float *out_o, *out_mu, *out_lv;
};

// 8-WG slab-group barrier (flags agent-scope -> correct on any placement).
DEV void gbar_g(u32* flg, int slice, u32 k)
{
    asm volatile("s_waitcnt vmcnt(0)" ::: "memory");
    __syncthreads();
    if (threadIdx.x == 0)
        __hip_atomic_store(&flg[slice * 16], k, __ATOMIC_RELAXED, __HIP_MEMORY_SCOPE_AGENT);
    if (threadIdx.x < 8) {
        while (__hip_atomic_load(&flg[threadIdx.x * 16], __ATOMIC_RELAXED,
                                 __HIP_MEMORY_SCOPE_AGENT) < k)
            __builtin_amdgcn_s_sleep(1);
    }
    __syncthreads();
}

// ---------------------------------------------------------------------------
__global__ void k_cvt(const float* __restrict__ src, bf16* __restrict__ dst, int n)
{
    int i = (blockIdx.x * blockDim.x + threadIdx.x) * 4;
    if (i < n) {
        float4 v = *reinterpret_cast<const float4*>(src + i);
        *reinterpret_cast<u32*>(dst + i)     = pk2(v.x, v.y);
        *reinterpret_cast<u32*>(dst + i + 2) = pk2(v.z, v.w);
    }
}

// ---------------------------------------------------------------------------
// Stage slab rows [r0,+16) x [head(K1) | body(CH)] into abuf.
// HMODE: 0 = plain cached head (x_b), 1 = FAST-dependent, 2 = device-scope.
// ---------------------------------------------------------------------------
template <bool FAST, int HMODE>
DEV void stage_act(bf16* abuf, int tid, int r0,
                   const bf16* head, long hs, int K1,
                   const bf16* body, long bs)
{
    const int CHN = (K1 + CH) >> 3;
    const int TOT = 16 * CHN;
    for (int idx = tid; idx < TOT; idx += 512) {
        const int row = idx / CHN;
        const int k = (idx - row * CHN) * 8;
        bf16x8 v;
        if (k < K1) {
            const bf16* s = head + (long)(r0 + row) * hs + k;
            if constexpr (HMODE == 0)      v = ldfrag(s);
            else if constexpr (HMODE == 1) v = ldx16<FAST>(s);
            else                           v = ldx16<false>(s);
        } else {
            v = ldx16<FAST>(body + (long)(r0 + row) * bs + (k - K1));
        }
        *reinterpret_cast<bf16x8*>(abuf + (long)row * APITCH + k) = v;
    }
    __syncthreads();
}

// ---------------------------------------------------------------------------
// GRU compute (r14 verbatim).
// ---------------------------------------------------------------------------
template <bool FAST>
DEV void gru_compute(const bf16* abuf, int r0, int n0, int lane, int wave,
                     const bf16* __restrict__ Wih, const bf16* __restrict__ Whh,
                     const float* __restrict__ bih, const float* __restrict__ bhh,
                     const float* __restrict__ Efin,
                     float* __restrict__ Efo, bf16* __restrict__ Ebo)
{
    const int lr = lane & 15, lkE = (lane >> 4) * 8;
    const int c = n0 + wave * 16 + lr;
    const bf16* arow = abuf + (long)lr * APITCH;

    f32x4 acc[4] = {};
#pragma unroll 4
    for (int k = 0; k < CIN; k += 32) {
        bf16x8 a = *reinterpret_cast<const bf16x8*>(arow + k + lkE);
#pragma unroll
        for (int g = 0; g < 3; ++g) {
            bf16x8 b = ldfrag(Wih + ((long)g * CH + c) * CIN + k + lkE);
            const int grp = (g == 2) ? 2 : g;
            acc[grp] = MFMA(a, b, acc[grp]);
        }
    }
#pragma unroll 4
    for (int k = 0; k < CH; k += 32) {
        bf16x8 a = *reinterpret_cast<const bf16x8*>(arow + CIN + k + lkE);
#pragma unroll
        for (int g = 0; g < 3; ++g) {
            bf16x8 b = ldfrag(Whh + ((long)g * CH + c) * CH + k + lkE);
            const int grp = (g == 2) ? 3 : g;
            acc[grp] = MFMA(a, b, acc[grp]);
        }
    }

    const float b0r = bih[c] + bhh[c];
    const float b0z = bih[CH + c] + bhh[CH + c];
    const float bin = bih[2 * CH + c];
    const float bhn = bhh[2 * CH + c];
    const int rbase = r0 + (lane >> 4) * 4;
#pragma unroll
    for (int i = 0; i < 4; ++i) {
        const int row = rbase + i;
        float r = sigmoidf_(acc[0][i] + b0r);
        float u = sigmoidf_(acc[1][i] + b0z);
        float n = tanhf(acc[2][i] + bin + r * (acc[3][i] + bhn));
        float en = (1.0f - u) * n + u * Efin[(long)row * CH + c];
        Efo[(long)row * CH + c] = en;
        float vB = __shfl_xor(en, 1);
        if (!(lane & 1))
            stx4<FAST>(Ebo + (long)row * CH + c, pk2(en, vB));
    }
}

// ---------------------------------------------------------------------------
template <bool FAST>
DEV void lin_compute(const bf16* abuf, int r0, int n0, int lane, int wave, int Ktot,
                     const bf16* __restrict__ W,
                     const float* __restrict__ bias, bf16* __restrict__ Out)
{
    const int lr = lane & 15, lkE = (lane >> 4) * 8;
    const int c = n0 + wave * 16 + lr;
    const bf16* arow = abuf + (long)lr * APITCH;
    const bf16* wrow = W + (long)c * Ktot;

    f32x4 acc = {};
#pragma unroll 4
    for (int k = 0; k < CH; k += 32) {
        bf16x8 a = *reinterpret_cast<const bf16x8*>(arow + (Ktot - CH) + k + lkE);
        bf16x8 b = ldfrag(wrow + (Ktot - CH) + k + lkE);
        acc = MFMA(a, b, acc);
    }
    if (Ktot > CH) {
#pragma unroll 4
        for (int k = 0; k < CZ; k += 32) {
            bf16x8 a = *reinterpret_cast<const bf16x8*>(arow + k + lkE);
            bf16x8 b = ldfrag(wrow + k + lkE);
            acc = MFMA(a, b, acc);
        }
    }

    const float bb = bias[c];
    const int rbase = r0 + (lane >> 4) * 4;
#pragma unroll
    for (int i = 0; i < 4; ++i) {
        float v = acc[i] + bb;
        float vB = __shfl_xor(v, 1);
        if (!(lane & 1))
            stx4<FAST>(Out + (long)(rbase + i) * CD + c, pk2(v, vB));
    }
}

// ---------------------------------------------------------------------------
template <bool FAST, int MODE>
DEV void phase_tail2(const Prm& p, int t, int slab, int slice, int tid,
                     int lane, int wave, float* Ra, float* Rs,
                     const bf16* __restrict__ A,
                     const bf16* __restrict__ Wa, const bf16* __restrict__ Wb,
                     const float* __restrict__ ba, const float* __restrict__ bb)
{
    const int lr = lane & 15, lkE = (lane >> 4) * 8;
    const int mb = slab * 16;
    const int nb = slice * 16;
    f32x4 am = {}, as = {};
    const int k0 = wave * 128;
#pragma unroll
    for (int kk = 0; kk < 128; kk += 32) {
        const int k = k0 + kk;
        bf16x8 a  = ldx16<FAST>(A + (long)(mb + lr) * CD + k + lkE);
        bf16x8 bm = ldfrag(Wa + (long)(nb + lr) * CD + k + lkE);
        bf16x8 bs = ldfrag(Wb + (long)(nb + lr) * CD + k + lkE);
        am = MFMA(a, bm, am);
        as = MFMA(a, bs, as);
    }
    __syncthreads();
#pragma unroll
    for (int i = 0; i < 4; ++i) {
        Ra[(wave * 16 + (lane >> 4) * 4 + i) * 17 + lr] = am[i];
        Rs[(wave * 16 + (lane >> 4) * 4 + i) * 17 + lr] = as[i];
    }
    __syncthreads();
    if (tid < 256) {
        const int trow = tid >> 4, tcol = tid & 15;
        float vm = 0.f, vs = 0.f;
#pragma unroll
        for (int w = 0; w < 8; ++w) {
            vm += Ra[(w * 16 + trow) * 17 + tcol];
            vs += Rs[(w * 16 + trow) * 17 + tcol];
        }
        const int row = mb + trow, col = nb + tcol;
        if constexpr (MODE == 0) {
            float mu = vm + ba[col];
            float lv = softplusf_(vs + bb[col]);
            float e  = p.eps_q[(long)row * CW * CZ + (long)t * CZ + col];
            float z  = mu + expf(0.5f * lv) * e;
            p.out_mu[(long)row * CW * CZ + (long)t * CZ + col] = mu;
            p.out_lv[(long)row * CW * CZ + (long)t * CZ + col] = lv;
            stx4<FAST>(p.ztmp_f + (long)row * CZ + col, __float_as_uint(z));
        } else {
            float m  = vm + ba[col];
            float sg = softplusf_(vs + bb[col]);
            float e  = p.eps_p[(long)row * CW * COUT + (long)t * COUT + col];
            p.out_o[(long)row * CW * COUT + (long)t * COUT + col] = m + sg * e;
        }
    }
}

// ---------------------------------------------------------------------------
// Planar flows + LGSSM: ztlg store is ALWAYS device-scope (crosses to P XCDs).
// ---------------------------------------------------------------------------
template <bool FAST>
DEV void phase_flows2(const Prm& p, int rowbase, int tid, int t, float* zl, float* ps)
{
    const int rg = tid >> 8;
    const int sub = tid & 255;
    const int c = sub & 127, half = sub >> 7;
    const int row = rowbase + rg;
    float* zrow = zl + rg * CZ;
    float* pall = ps + rg * 2 * CZ;

    if (half == 0)
        zrow[c] = __uint_as_float(ldx4<FAST>(p.ztmp_f + (long)row * CZ + c));
    __syncthreads();

#pragma unroll 1
    for (int kf = 0; kf < 3; ++kf) {
        const float* wr = p.Wp + ((long)kf * CZ + c) * CZ + half * 64;
        const float* zh = zrow + half * 64;
        float s = 0.f;
#pragma unroll
        for (int j = 0; j < 64; j += 4) {
            float4 w = *reinterpret_cast<const float4*>(wr + j);
            s += zh[j] * w.x + zh[j + 1] * w.y + zh[j + 2] * w.z + zh[j + 3] * w.w;
        }
        pall[half * CZ + c] = s;
        __syncthreads();
        if (half == 0) {
            float sf = pall[c] + pall[CZ + c] + p.bp[kf * CZ + c];
            zrow[c] += p.up[kf] * tanhf(sf);
        }
        __syncthreads();
    }
    {
        const float* wr = p.Wlg + (long)c * CZ + half * 64;
        const float* zh = zrow + half * 64;
        float s = 0.f;
#pragma unroll
        for (int j = 0; j < 64; j += 4) {
            float4 w = *reinterpret_cast<const float4*>(wr + j);
            s += zh[j] * w.x + zh[j + 1] * w.y + zh[j + 2] * w.z + zh[j + 3] * w.w;
        }
        pall[half * CZ + c] = s;
        __syncthreads();
        if (half == 0) {
            float zt = pall[c] + pall[CZ + c] + p.blg[c];
            float ztB = __shfl_xor(zt, 1);
            if (!(c & 1)) {
                // Q->P cross-XCD: device scope always
                stx4<false>(p.ztlg + ((size_t)(t & 1) * CB + row) * CZ + c, pk2(zt, ztB));
                // Q-internal: fast path
                stx4<FAST>(p.zflow + ((size_t)((t + 1) & 1) * CB + row) * CZ + c,
                           pk2(zrow[c], zrow[c + 1]));
            }
        }
    }
}

// ---------------------------------------------------------------------------
template <bool FAST>
DEV void run_q(const Prm& p, int slab, int slice, int tid,
               bf16* abuf, float* Ra, float* Rs, float* ZLp, float* PSp)
{
    const int lane = tid & 63, wave = tid >> 6;
    const int r0 = slab * 16, n0 = slice * 128;
    u32* qb = p.qbar + slab * 8 * 16;
    u32 bk = 0;
#pragma unroll 1
    for (int t = 0; t < CW; ++t) {
        const int bi = t & 1;
        const bf16*  eb_i = bi ? p.e_b1 : p.e_b0;
        const float* ef_i = bi ? p.e_f1 : p.e_f0;
        bf16*  eb_o = bi ? p.e_b0 : p.e_b1;
        float* ef_o = bi ? p.e_f0 : p.e_f1;

        stage_act<FAST, 0>(abuf, tid, r0, p.x_b + (long)t * CIN, (long)CW * CIN,
                           CIN, eb_i, CH);
        gru_compute<FAST>(abuf, r0, n0, lane, wave, p.Wih_qb, p.Whh_qb,
                          p.bih_q, p.bhh_q, ef_i, ef_o, eb_o);
        gbar_g(qb, slice, ++bk);
        stage_act<FAST, 1>(abuf, tid, r0, p.zflow + (size_t)bi * CB * CZ,
                           CZ, CZ, eb_o, CH);
        lin_compute<FAST>(abuf, r0, n0, lane, wave, CZ + CH, p.Wd_qb, p.bd_q, p.dvec_b);
        gbar_g(qb, slice, ++bk);
        phase_tail2<FAST, 0>(p, t, slab, slice, tid, lane, wave, Ra, Rs,
                             p.dvec_b, p.Wmu_qb, p.Wsg_qb, p.bmu_q, p.bsig_q);
        gbar_g(qb, slice, ++bk);
        if (t >= 2) {
            if (tid == 0) {
                while ((int)__hip_atomic_load(&p.pdone[slab * 16], __ATOMIC_RELAXED,
                                              __HIP_MEMORY_SCOPE_AGENT) < t - 1)
                    __builtin_amdgcn_s_sleep(2);
            }
            __syncthreads();
        }
        phase_flows2<FAST>(p, slab * 16 + slice * 2, tid, t, ZLp, PSp);
        gbar_g(qb, slice, ++bk);
        if (slice == 0 && tid == 0)
            __hip_atomic_store(&p.zbar[slab * 16], (u32)(t + 1),
                               __ATOMIC_RELAXED, __HIP_MEMORY_SCOPE_AGENT);
    }
}

template <bool FAST>
DEV void run_p(const Prm& p, int slab, int slice, int tid,
               bf16* abuf, float* Ra, float* Rs)
{
    const int lane = tid & 63, wave = tid >> 6;
    const int r0 = slab * 16, n0 = slice * 128;
    u32* pb = p.pbar + slab * 8 * 16;
    u32 bk = 0;
#pragma unroll 1
    for (int t = 0; t < CW; ++t) {
        if (tid == 0) {
            while (__hip_atomic_load(&p.zbar[slab * 16], __ATOMIC_RELAXED,
                                     __HIP_MEMORY_SCOPE_AGENT) < (u32)(t + 1))
                __builtin_amdgcn_s_sleep(2);
        }
        __syncthreads();

        const int bi = t & 1;
        const bf16*  db_i = bi ? p.d_b1 : p.d_b0;
        const float* df_i = bi ? p.d_f1 : p.d_f0;
        bf16*  db_o = bi ? p.d_b0 : p.d_b1;
        float* df_o = bi ? p.d_f0 : p.d_f1;

        // head ztlg comes from Q XCDs -> device-scope loads (HMODE 2)
        stage_act<FAST, 2>(abuf, tid, r0, p.ztlg + (size_t)bi * CB * CZ,
                           CZ, CZ, db_i, CH);
        gru_compute<FAST>(abuf, r0, n0, lane, wave, p.Wih_pb, p.Whh_pb,
                          p.bih_p, p.bhh_p, df_i, df_o, db_o);
        gbar_g(pb, slice, ++bk);
        if (slice == 0 && tid == 0)
            __hip_atomic_store(&p.pdone[slab * 16], (u32)(t + 1),
                               __ATOMIC_RELAXED, __HIP_MEMORY_SCOPE_AGENT);
        stage_act<FAST, 0>(abuf, tid, r0, nullptr, 0, 0, db_o, CH);
        lin_compute<FAST>(abuf, r0, n0, lane, wave, CH, p.Wd_pb, p.bd_p, p.ddvec_b);
        gbar_g(pb, slice, ++bk);
        phase_tail2<FAST, 1>(p, t, slab, slice, tid, lane, wave, Ra, Rs,
                             p.ddvec_b, p.Wmu_pb, p.Wsg_pb, p.bmu_p, p.bsig_p);
    }
}

// ---------------------------------------------------------------------------
__launch_bounds__(512)
__global__ void mega(Prm p)
{
    extern __shared__ char smem[];
    bf16*  abuf = (bf16*)smem;
    float* Ra   = (float*)(smem + ABUF_BYTES);
    float* Rs   = Ra + REDN;
    float* ZLp  = (float*)(smem + ABUF_BYTES + RED2_BYTES);
    float* PSp  = ZLp + 2 * CZ;
    __shared__ int s_fast;

    const int wg = blockIdx.x, tid = threadIdx.x;
    const int gid = wg & 7, m = wg >> 3;          // m 0..31
    const bool isQ = gid < 4;
    const int slab = (isQ ? gid : gid - 4) * 4 + (m >> 3);   // 4 slabs per XCD
    const int slice = m & 7;

    // ---- startup: publish physical XCD id, verify nominal groups ----
    const u32 myx = (u32)__builtin_amdgcn_s_getreg(XCC_GETREG);
    if (tid == 0) {
        __hip_atomic_store(&p.xcc[wg * 16], myx, __ATOMIC_RELAXED, __HIP_MEMORY_SCOPE_AGENT);
        __hip_atomic_fetch_add(p.cnt, 1u, __ATOMIC_RELAXED, __HIP_MEMORY_SCOPE_AGENT);
        while (__hip_atomic_load(p.cnt, __ATOMIC_RELAXED, __HIP_MEMORY_SCOPE_AGENT) < 256u)
            __builtin_amdgcn_s_sleep(2);
    }
    __syncthreads();
    if (tid < 64) {
        bool eq = true;
        if (tid < 32) {
            u32 o = __hip_atomic_load(&p.xcc[(gid + 8 * tid) * 16],
                                      __ATOMIC_RELAXED, __HIP_MEMORY_SCOPE_AGENT);
            eq = (o == myx);
        }
        unsigned long long b = __ballot(eq);
        if (tid == 0) s_fast = (b == ~0ull) ? 1 : 0;
    }
    __syncthreads();
    const bool fast = (s_fast != 0);

    if (isQ) {
        if (fast) run_q<true>(p, slab, slice, tid, abuf, Ra, Rs, ZLp, PSp);
        else      run_q<false>(p, slab, slice, tid, abuf, Ra, Rs, ZLp, PSp);
    } else {
        if (fast) run_p<true>(p, slab, slice, tid, abuf, Ra, Rs);
        else      run_p<false>(p, slab, slice, tid, abuf, Ra, Rs);
    }
}

// ---------------------------------------------------------------------------
// Host driver
// ---------------------------------------------------------------------------
extern "C" void kernel_launch(void* const* d_in, const int* in_sizes, int n_in,
                              void* d_out, int out_size, void* d_ws, size_t ws_size,
                              hipStream_t stream)
{
    Prm p;
    const float* x      = (const float*)d_in[0];
    p.eps_q  = (const float*)d_in[1];
    p.eps_p  = (const float*)d_in[2];
    const float* Wih_q  = (const float*)d_in[3];
    const float* Whh_q  = (const float*)d_in[4];
    p.bih_q  = (const float*)d_in[5];
    p.bhh_q  = (const float*)d_in[6];
    const float* Wd_q   = (const float*)d_in[7];
    p.bd_q   = (const float*)d_in[8];
    const float* Wmu_q  = (const float*)d_in[9];
    p.bmu_q  = (const float*)d_in[10];
    const float* Wsig_q = (const float*)d_in[11];
    p.bsig_q = (const float*)d_in[12];
    p.Wp     = (const float*)d_in[13];
    p.bp     = (const float*)d_in[14];
    p.up     = (const float*)d_in[15];
    p.Wlg    = (const float*)d_in[16];
    p.blg    = (const float*)d_in[17];
    const float* Wih_p  = (const float*)d_in[18];
    const float* Whh_p  = (const float*)d_in[19];
    p.bih_p  = (const float*)d_in[20];
    p.bhh_p  = (const float*)d_in[21];
    const float* Wd_p   = (const float*)d_in[22];
    p.bd_p   = (const float*)d_in[23];
    const float* Wmu_p  = (const float*)d_in[24];
    p.bmu_p  = (const float*)d_in[25];
    const float* Wsig_p = (const float*)d_in[26];
    p.bsig_p = (const float*)d_in[27];

    p.out_o  = (float*)d_out;
    p.out_mu = p.out_o + (size_t)CB * CW * COUT;
    p.out_lv = p.out_mu + (size_t)CB * CW * CZ;

    char* wp_ = (char*)d_ws;
    auto carve = [&](size_t bytes) -> void* {
        void* q = (void*)wp_;
        wp_ += (bytes + 255) & ~(size_t)255;
        return q;
    };
    p.e_f0 = (float*)carve((size_t)CB * CH * 4);
    p.e_f1 = (float*)carve((size_t)CB * CH * 4);
    p.d_f0 = (float*)carve((size_t)CB * CH * 4);
    p.d_f1 = (float*)carve((size_t)CB * CH * 4);
    p.e_b0 = (bf16*)carve((size_t)CB * CH * 2);
    p.e_b1 = (bf16*)carve((size_t)CB * CH * 2);
    p.d_b0 = (bf16*)carve((size_t)CB * CH * 2);
    p.d_b1 = (bf16*)carve((size_t)CB * CH * 2);
    p.ztmp_f  = (float*)carve((size_t)CB * CZ * 4);
    p.dvec_b  = (bf16*)carve((size_t)CB * CD * 2);
    p.ddvec_b = (bf16*)carve((size_t)CB * CD * 2);
    p.zflow   = (bf16*)carve((size_t)2 * CB * CZ * 2);
    p.ztlg    = (bf16*)carve((size_t)2 * CB * CZ * 2);
    p.qbar    = (u32*)carve((size_t)16 * 8 * 16 * 4);
    p.pbar    = (u32*)carve((size_t)16 * 8 * 16 * 4);
    p.zbar    = (u32*)carve((size_t)16 * 16 * 4);
    p.pdone   = (u32*)carve((size_t)16 * 16 * 4);
    p.xcc     = (u32*)carve((size_t)256 * 16 * 4);
    p.cnt     = (u32*)carve(256);
    bf16* x_b    = (bf16*)carve((size_t)CB * CW * CIN * 2);
    bf16* Wih_qb = (bf16*)carve((size_t)3 * CH * CIN * 2);
    bf16* Whh_qb = (bf16*)carve((size_t)3 * CH * CH * 2);
    bf16* Wd_qb  = (bf16*)carve((size_t)CD * (CZ + CH) * 2);
    bf16* Wmu_qb = (bf16*)carve((size_t)CZ * CD * 2);
    bf16* Wsg_qb = (bf16*)carve((size_t)CZ * CD * 2);
    bf16* Wih_pb = (bf16*)carve((size_t)3 * CH * CZ * 2);
    bf16* Whh_pb = (bf16*)carve((size_t)3 * CH * CH * 2);
    bf16* Wd_pb  = (bf16*)carve((size_t)CD * CH * 2);
    bf16* Wmu_pb = (bf16*)carve((size_t)COUT * CD * 2);
    bf16* Wsg_pb = (bf16*)carve((size_t)COUT * CD * 2);
    p.x_b = x_b;       p.Wih_qb = Wih_qb; p.Whh_qb = Whh_qb;
    p.Wd_qb = Wd_qb;   p.Wmu_qb = Wmu_qb; p.Wsg_qb = Wsg_qb;
    p.Wih_pb = Wih_pb; p.Whh_pb = Whh_pb; p.Wd_pb = Wd_pb;
    p.Wmu_pb = Wmu_pb; p.Wsg_pb = Wsg_pb;

    hipMemsetAsync(p.e_f0, 0, (size_t)CB * CH * 4, stream);
    hipMemsetAsync(p.d_f0, 0, (size_t)CB * CH * 4, stream);
    hipMemsetAsync(p.e_b0, 0, (size_t)CB * CH * 2, stream);
    hipMemsetAsync(p.d_b0, 0, (size_t)CB * CH * 2, stream);
    hipMemsetAsync(p.zflow, 0, (size_t)CB * CZ * 2, stream);
    hipMemsetAsync(p.qbar, 0, (size_t)16 * 8 * 16 * 4, stream);
    hipMemsetAsync(p.pbar, 0, (size_t)16 * 8 * 16 * 4, stream);
    hipMemsetAsync(p.zbar, 0, (size_t)16 * 16 * 4, stream);
    hipMemsetAsync(p.pdone, 0, (size_t)16 * 16 * 4, stream);
    hipMemsetAsync(p.xcc, 0, (size_t)256 * 16 * 4, stream);
    hipMemsetAsync(p.cnt, 0, 256, stream);

    auto cvt = [&](const float* s, bf16* d, size_t n) {
        k_cvt<<<dim3((unsigned)((n / 4 + 255) / 256)), dim3(256), 0, stream>>>(s, d, (int)n);
    };
    cvt(x,      x_b,    (size_t)CB * CW * CIN);
    cvt(Wih_q,  Wih_qb, (size_t)3 * CH * CIN);
    cvt(Whh_q,  Whh_qb, (size_t)3 * CH * CH);
    cvt(Wd_q,   Wd_qb,  (size_t)CD * (CZ + CH));
    cvt(Wmu_q,  Wmu_qb, (size_t)CZ * CD);
    cvt(Wsig_q, Wsg_qb, (size_t)CZ * CD);
    cvt(Wih_p,  Wih_pb, (size_t)3 * CH * CZ);
    cvt(Whh_p,  Whh_pb, (size_t)3 * CH * CH);
    cvt(Wd_p,   Wd_pb,  (size_t)CD * CH);
    cvt(Wmu_p,  Wmu_pb, (size_t)COUT * CD);
    cvt(Wsig_p, Wsg_pb, (size_t)COUT * CD);

    mega<<<dim3(256), dim3(512), SMEM_BYTES, stream>>>(p);
}

// Round 17
// 8089.214 us; speedup vs baseline: 1.1324x; 1.0766x over previous
//
#include <hip/hip_runtime.h>

// ---------------------------------------------------------------------------
// OmniAnomaly forward, round 17: r16 (Q/P XCD specialization, 8.71ms) with
// de-serialized loads: batched staging (one vmcnt wait per 4 loads), software-
// pipelined weight streams (4-deep x3 in GRU, 8-deep in lin), batched tail
// loads. Structure/barriers/protocols identical to r16.
// B=256, W=128, IN=128, H=1024, Z=128, D=1024, OUT=128, K=3 flows
// ---------------------------------------------------------------------------

typedef __bf16 bf16;
typedef __bf16 bf16x8 __attribute__((ext_vector_type(8)));
typedef float  f32x4  __attribute__((ext_vector_type(4)));
typedef unsigned u32;

static constexpr int CB   = 256;
static constexpr int CW   = 128;
static constexpr int CIN  = 128;
static constexpr int CH   = 1024;
static constexpr int CZ   = 128;
static constexpr int CD   = 1024;
static constexpr int COUT = 128;

static constexpr int APITCH     = 1160;                      // 1152 + 8 pad
static constexpr int ABUF_BYTES = 16 * APITCH * 2;           // 37120
static constexpr int REDN       = 8 * 16 * 17;
static constexpr int RED2_BYTES = 2 * REDN * 4;              // 17408
static constexpr int FLOW_BYTES = (2 * CZ + 2 * 2 * CZ) * 4; // 3072
static constexpr int SMEM_BYTES = ABUF_BYTES + RED2_BYTES + FLOW_BYTES; // 57600

// s_getreg imm: ID=20 (HW_REG_XCC_ID), offset 0, width 32 -> 20 | (31<<11)
static constexpr int XCC_GETREG = 20 | (31 << 11);

#define DEV static __device__ __forceinline__

DEV float sigmoidf_(float x) { return 1.0f / (1.0f + expf(-x)); }
DEV float softplusf_(float x) { return x > 20.0f ? x : log1pf(expf(x)); }
DEV bf16x8 ldfrag(const bf16* p) { return *reinterpret_cast<const bf16x8*>(p); }

#define MFMA(a, b, c) __builtin_amdgcn_mfma_f32_16x16x32_bf16((a), (b), (c), 0, 0, 0)

// ---- coherent accesses ----
// with-wait variants (for occasional single loads)
template <bool FAST> DEV bf16x8 ldx16(const bf16* p) {
    bf16x8 v;
    if constexpr (FAST)
        asm volatile("global_load_dwordx4 %0, %1, off sc0\n\ts_waitcnt vmcnt(0)"
                     : "=v"(v) : "v"(p) : "memory");
    else
        asm volatile("global_load_dwordx4 %0, %1, off sc0 sc1\n\ts_waitcnt vmcnt(0)"
                     : "=v"(v) : "v"(p) : "memory");
    return v;
}
template <bool FAST> DEV u32 ldx4(const void* p) {
    u32 v;
    if constexpr (FAST)
        asm volatile("global_load_dword %0, %1, off sc0\n\ts_waitcnt vmcnt(0)"
                     : "=v"(v) : "v"(p) : "memory");
    else
        asm volatile("global_load_dword %0, %1, off sc0 sc1\n\ts_waitcnt vmcnt(0)"
                     : "=v"(v) : "v"(p) : "memory");
    return v;
}
// no-wait variant (batched; MUST be followed by vm_wait0 before use)
template <bool FAST> DEV bf16x8 ldx16_nw(const bf16* p) {
    bf16x8 v;
    if constexpr (FAST)
        asm volatile("global_load_dwordx4 %0, %1, off sc0"
                     : "=v"(v) : "v"(p) : "memory");
    else
        asm volatile("global_load_dwordx4 %0, %1, off sc0 sc1"
                     : "=v"(v) : "v"(p) : "memory");
    return v;
}
DEV void vm_wait0() {
    asm volatile("s_waitcnt vmcnt(0)" ::: "memory");
    __builtin_amdgcn_sched_barrier(0);   // rule 18: pin register consumers after wait
}
template <bool FAST> DEV void stx4(void* p, u32 v) {
    if constexpr (FAST)
        asm volatile("global_store_dword %0, %1, off sc0" :: "v"(p), "v"(v) : "memory");
    else
        asm volatile("global_store_dword %0, %1, off sc0 sc1" :: "v"(p), "v"(v) : "memory");
}
DEV u32 pk2(float a, float b) {
    union { bf16 h[2]; u32 u; } r;
    r.h[0] = (bf16)a; r.h[1] = (bf16)b;
    return r.u;
}

struct Prm {
    const float *eps_q, *eps_p;
    const float *bih_q, *bhh_q, *bd_q, *bmu_q, *bsig_q;
    const float *Wp, *bp, *up, *Wlg, *blg;
    const float *bih_p, *bhh_p, *bd_p, *bmu_p, *bsig_p;
    const bf16 *x_b, *Wih_qb, *Whh_qb, *Wd_qb, *Wmu_qb, *Wsg_qb;
    const bf16 *Wih_pb, *Whh_pb, *Wd_pb, *Wmu_pb, *Wsg_pb;
    float *e_f0, *e_f1, *d_f0, *d_f1;
    bf16 *e_b0, *e_b1, *d_b0, *d_b1;
    float *ztmp_f;
    bf16 *dvec_b, *ddvec_b;
    bf16 *zflow;    // [2][CB][CZ]  (Q-internal)
    bf16 *ztlg;     // [2][CB][CZ]  (Q->P, ALWAYS device-scope sc0sc1)
    u32 *qbar, *pbar;
    u32 *zbar, *pdone;
    u32 *xcc, *cnt;
    float *out_o, *out_mu, *out_lv;
};

// 8-WG slab-group barrier (flags agent-scope -> correct on any placement).
DEV void gbar_g(u32* flg, int slice, u32 k)
{
    asm volatile("s_waitcnt vmcnt(0)" ::: "memory");
    __syncthreads();
    if (threadIdx.x == 0)
        __hip_atomic_store(&flg[slice * 16], k, __ATOMIC_RELAXED, __HIP_MEMORY_SCOPE_AGENT);
    if (threadIdx.x < 8) {
        while (__hip_atomic_load(&flg[threadIdx.x * 16], __ATOMIC_RELAXED,
                                 __HIP_MEMORY_SCOPE_AGENT) < k)
            __builtin_amdgcn_s_sleep(1);
    }
    __syncthreads();
}

// ---------------------------------------------------------------------------
__global__ void k_cvt(const float* __restrict__ src, bf16* __restrict__ dst, int n)
{
    int i = (blockIdx.x * blockDim.x + threadIdx.x) * 4;
    if (i < n) {
        float4 v = *reinterpret_cast<const float4*>(src + i);
        *reinterpret_cast<u32*>(dst + i)     = pk2(v.x, v.y);
        *reinterpret_cast<u32*>(dst + i + 2) = pk2(v.z, v.w);
    }
}

// ---------------------------------------------------------------------------
// Stage slab rows [r0,+16) x [head(K1) | body(1024)] into abuf.
// Body: exactly 4 chunks/thread, BATCHED (issue 4 no-wait, 1 wait, LDS write).
// HMODE: 0 = plain cached head, 1 = FAST-dependent, 2 = device-scope.
// ---------------------------------------------------------------------------
template <bool FAST, int HMODE>
DEV void stage_act(bf16* abuf, int tid, int r0,
                   const bf16* head, long hs, int K1,
                   const bf16* body, long bs)
{
    // body: 16 rows x 128 chunks = 2048 chunks, 4 per thread
    bf16x8 v[4];
    long dst[4];
#pragma unroll
    for (int j = 0; j < 4; ++j) {
        const int idx = tid + j * 512;
        const int row = idx >> 7;
        const int k = (idx & 127) * 8;
        v[j] = ldx16_nw<FAST>(body + (long)(r0 + row) * bs + k);
        dst[j] = (long)row * APITCH + K1 + k;
    }
    vm_wait0();
#pragma unroll
    for (int j = 0; j < 4; ++j)
        *reinterpret_cast<bf16x8*>(abuf + dst[j]) = v[j];
    // head: 16 x (K1/8) chunks (<=256), one per thread
    if (K1 > 0) {
        const int HC = K1 >> 3;
        for (int idx = tid; idx < 16 * HC; idx += 512) {
            const int row = idx / HC;
            const int k = (idx - row * HC) * 8;
            const bf16* s = head + (long)(r0 + row) * hs + k;
            bf16x8 hv;
            if constexpr (HMODE == 0)      hv = ldfrag(s);
            else if constexpr (HMODE == 1) hv = ldx16<FAST>(s);
            else                           hv = ldx16<false>(s);
            *reinterpret_cast<bf16x8*>(abuf + (long)row * APITCH + k) = hv;
        }
    }
    __syncthreads();
}

// ---------------------------------------------------------------------------
// GRU compute: CIN segment batch-loaded (12 in flight); CH segment with
// explicit 4-deep x 3-stream rotating prefetch (12 in flight steady-state).
// ---------------------------------------------------------------------------
template <bool FAST>
DEV void gru_compute(const bf16* abuf, int r0, int n0, int lane, int wave,
                     const bf16* __restrict__ Wih, const bf16* __restrict__ Whh,
                     const float* __restrict__ bih, const float* __restrict__ bhh,
                     const float* __restrict__ Efin,
                     float* __restrict__ Efo, bf16* __restrict__ Ebo)
{
    const int lr = lane & 15, lkE = (lane >> 4) * 8;
    const int c = n0 + wave * 16 + lr;
    const bf16* arow = abuf + (long)lr * APITCH;

    f32x4 acc[4] = {};

    // ---- CIN segment (4 blocks): batch all 12 weight loads ----
    {
        bf16x8 wv[4][3];
#pragma unroll
        for (int j = 0; j < 4; ++j)
#pragma unroll
            for (int g = 0; g < 3; ++g)
                wv[j][g] = ldfrag(Wih + ((long)g * CH + c) * CIN + j * 32 + lkE);
#pragma unroll
        for (int j = 0; j < 4; ++j) {
            bf16x8 a = *reinterpret_cast<const bf16x8*>(arow + j * 32 + lkE);
            acc[0] = MFMA(a, wv[j][0], acc[0]);
            acc[1] = MFMA(a, wv[j][1], acc[1]);
            acc[2] = MFMA(a, wv[j][2], acc[2]);
        }
    }
    // ---- CH segment (32 blocks): 4-deep rotating prefetch ----
    {
        const bf16* wp0 = Whh + ((long)0 * CH + c) * CH + lkE;
        const bf16* wp1 = Whh + ((long)1 * CH + c) * CH + lkE;
        const bf16* wp2 = Whh + ((long)2 * CH + c) * CH + lkE;
        bf16x8 wv[4][3];
#pragma unroll
        for (int j = 0; j < 4; ++j) {
            wv[j][0] = ldfrag(wp0 + j * 32);
            wv[j][1] = ldfrag(wp1 + j * 32);
            wv[j][2] = ldfrag(wp2 + j * 32);
        }
#pragma unroll
        for (int kb = 0; kb < 32; ++kb) {
            const int sl = kb & 3;
            bf16x8 a = *reinterpret_cast<const bf16x8*>(arow + CIN + kb * 32 + lkE);
            acc[0] = MFMA(a, wv[sl][0], acc[0]);
            acc[1] = MFMA(a, wv[sl][1], acc[1]);
            acc[3] = MFMA(a, wv[sl][2], acc[3]);
            if (kb < 28) {
                wv[sl][0] = ldfrag(wp0 + (kb + 4) * 32);
                wv[sl][1] = ldfrag(wp1 + (kb + 4) * 32);
                wv[sl][2] = ldfrag(wp2 + (kb + 4) * 32);
            }
        }
    }

    const float b0r = bih[c] + bhh[c];
    const float b0z = bih[CH + c] + bhh[CH + c];
    const float bin = bih[2 * CH + c];
    const float bhn = bhh[2 * CH + c];
    const int rbase = r0 + (lane >> 4) * 4;
#pragma unroll
    for (int i = 0; i < 4; ++i) {
        const int row = rbase + i;
        float r = sigmoidf_(acc[0][i] + b0r);
        float u = sigmoidf_(acc[1][i] + b0z);
        float n = tanhf(acc[2][i] + bin + r * (acc[3][i] + bhn));
        float en = (1.0f - u) * n + u * Efin[(long)row * CH + c];
        Efo[(long)row * CH + c] = en;
        float vB = __shfl_xor(en, 1);
        if (!(lane & 1))
            stx4<FAST>(Ebo + (long)row * CH + c, pk2(en, vB));
    }
}

// ---------------------------------------------------------------------------
// Linear compute: CH loop with 8-deep rotating prefetch; K1 segment batched.
// ---------------------------------------------------------------------------
template <bool FAST>
DEV void lin_compute(const bf16* abuf, int r0, int n0, int lane, int wave, int Ktot,
                     const bf16* __restrict__ W,
                     const float* __restrict__ bias, bf16* __restrict__ Out)
{
    const int lr = lane & 15, lkE = (lane >> 4) * 8;
    const int c = n0 + wave * 16 + lr;
    const bf16* arow = abuf + (long)lr * APITCH;
    const bf16* wrow = W + (long)c * Ktot;
    const int kofs = Ktot - CH;   // 0 or CZ

    f32x4 acc = {};
    {
        const bf16* wp = wrow + kofs + lkE;
        bf16x8 wv[8];
#pragma unroll
        for (int j = 0; j < 8; ++j) wv[j] = ldfrag(wp + j * 32);
#pragma unroll
        for (int kb = 0; kb < 32; ++kb) {
            const int sl = kb & 7;
            bf16x8 a = *reinterpret_cast<const bf16x8*>(arow + kofs + kb * 32 + lkE);
            acc = MFMA(a, wv[sl], acc);
            if (kb < 24) wv[sl] = ldfrag(wp + (kb + 8) * 32);
        }
    }
    if (Ktot > CH) {
        bf16x8 wv[4];
#pragma unroll
        for (int j = 0; j < 4; ++j) wv[j] = ldfrag(wrow + j * 32 + lkE);
#pragma unroll
        for (int j = 0; j < 4; ++j) {
            bf16x8 a = *reinterpret_cast<const bf16x8*>(arow + j * 32 + lkE);
            acc = MFMA(a, wv[j], acc);
        }
    }

    const float bb = bias[c];
    const int rbase = r0 + (lane >> 4) * 4;
#pragma unroll
    for (int i = 0; i < 4; ++i) {
        float v = acc[i] + bb;
        float vB = __shfl_xor(v, 1);
        if (!(lane & 1))
            stx4<FAST>(Out + (long)(rbase + i) * CD + c, pk2(v, vB));
    }
}

// ---------------------------------------------------------------------------
// Two-head tail: batched A-loads (4 no-wait + 1 wait), weights batch-loaded.
// ---------------------------------------------------------------------------
template <bool FAST, int MODE>
DEV void phase_tail2(const Prm& p, int t, int slab, int slice, int tid,
                     int lane, int wave, float* Ra, float* Rs,
                     const bf16* __restrict__ A,
                     const bf16* __restrict__ Wa, const bf16* __restrict__ Wb,
                     const float* __restrict__ ba, const float* __restrict__ bb)
{
    const int lr = lane & 15, lkE = (lane >> 4) * 8;
    const int mb = slab * 16;
    const int nb = slice * 16;
    f32x4 am = {}, as = {};
    const int k0 = wave * 128;
    bf16x8 av[4], bmv[4], bsv[4];
#pragma unroll
    for (int j = 0; j < 4; ++j) {
        const int k = k0 + j * 32;
        av[j]  = ldx16_nw<FAST>(A + (long)(mb + lr) * CD + k + lkE);
        bmv[j] = ldfrag(Wa + (long)(nb + lr) * CD + k + lkE);
        bsv[j] = ldfrag(Wb + (long)(nb + lr) * CD + k + lkE);
    }
    vm_wait0();
#pragma unroll
    for (int j = 0; j < 4; ++j) {
        am = MFMA(av[j], bmv[j], am);
        as = MFMA(av[j], bsv[j], as);
    }
    __syncthreads();
#pragma unroll
    for (int i = 0; i < 4; ++i) {
        Ra[(wave * 16 + (lane >> 4) * 4 + i) * 17 + lr] = am[i];
        Rs[(wave * 16 + (lane >> 4) * 4 + i) * 17 + lr] = as[i];
    }
    __syncthreads();
    if (tid < 256) {
        const int trow = tid >> 4, tcol = tid & 15;
        float vm = 0.f, vs = 0.f;
#pragma unroll
        for (int w = 0; w < 8; ++w) {
            vm += Ra[(w * 16 + trow) * 17 + tcol];
            vs += Rs[(w * 16 + trow) * 17 + tcol];
        }
        const int row = mb + trow, col = nb + tcol;
        if constexpr (MODE == 0) {
            float mu = vm + ba[col];
            float lv = softplusf_(vs + bb[col]);
            float e  = p.eps_q[(long)row * CW * CZ + (long)t * CZ + col];
            float z  = mu + expf(0.5f * lv) * e;
            p.out_mu[(long)row * CW * CZ + (long)t * CZ + col] = mu;
            p.out_lv[(long)row * CW * CZ + (long)t * CZ + col] = lv;
            stx4<FAST>(p.ztmp_f + (long)row * CZ + col, __float_as_uint(z));
        } else {
            float m  = vm + ba[col];
            float sg = softplusf_(vs + bb[col]);
            float e  = p.eps_p[(long)row * CW * COUT + (long)t * COUT + col];
            p.out_o[(long)row * CW * COUT + (long)t * COUT + col] = m + sg * e;
        }
    }
}

// ---------------------------------------------------------------------------
// Planar flows + LGSSM (r16 verbatim).
// ---------------------------------------------------------------------------
template <bool FAST>
DEV void phase_flows2(const Prm& p, int rowbase, int tid, int t, float* zl, float* ps)
{
    const int rg = tid >> 8;
    const int sub = tid & 255;
    const int c = sub & 127, half = sub >> 7;
    const int row = rowbase + rg;
    float* zrow = zl + rg * CZ;
    float* pall = ps + rg * 2 * CZ;

    if (half == 0)
        zrow[c] = __uint_as_float(ldx4<FAST>(p.ztmp_f + (long)row * CZ + c));
    __syncthreads();

#pragma unroll 1
    for (int kf = 0; kf < 3; ++kf) {
        const float* wr = p.Wp + ((long)kf * CZ + c) * CZ + half * 64;
        const float* zh = zrow + half * 64;
        float s = 0.f;
#pragma unroll
        for (int j = 0; j < 64; j += 4) {
            float4 w = *reinterpret_cast<const float4*>(wr + j);
            s += zh[j] * w.x + zh[j + 1] * w.y + zh[j + 2] * w.z + zh[j + 3] * w.w;
        }
        pall[half * CZ + c] = s;
        __syncthreads();
        if (half == 0) {
            float sf = pall[c] + pall[CZ + c] + p.bp[kf * CZ + c];
            zrow[c] += p.up[kf] * tanhf(sf);
        }
        __syncthreads();
    }
    {
        const float* wr = p.Wlg + (long)c * CZ + half * 64;
        const float* zh = zrow + half * 64;
        float s = 0.f;
#pragma unroll
        for (int j = 0; j < 64; j += 4) {
            float4 w = *reinterpret_cast<const float4*>(wr + j);
            s += zh[j] * w.x + zh[j + 1] * w.y + zh[j + 2] * w.z + zh[j + 3] * w.w;
        }
        pall[half * CZ + c] = s;
        __syncthreads();
        if (half == 0) {
            float zt = pall[c] + pall[CZ + c] + p.blg[c];
            float ztB = __shfl_xor(zt, 1);
            if (!(c & 1)) {
                stx4<false>(p.ztlg + ((size_t)(t & 1) * CB + row) * CZ + c, pk2(zt, ztB));
                stx4<FAST>(p.zflow + ((size_t)((t + 1) & 1) * CB + row) * CZ + c,
                           pk2(zrow[c], zrow[c + 1]));
            }
        }
    }
}

// ---------------------------------------------------------------------------
template <bool FAST>
DEV void run_q(const Prm& p, int slab, int slice, int tid,
               bf16* abuf, float* Ra, float* Rs, float* ZLp, float* PSp)
{
    const int lane = tid & 63, wave = tid >> 6;
    const int r0 = slab * 16, n0 = slice * 128;
    u32* qb = p.qbar + slab * 8 * 16;
    u32 bk = 0;
#pragma unroll 1
    for (int t = 0; t < CW; ++t) {
        const int bi = t & 1;
        const bf16*  eb_i = bi ? p.e_b1 : p.e_b0;
        const float* ef_i = bi ? p.e_f1 : p.e_f0;
        bf16*  eb_o = bi ? p.e_b0 : p.e_b1;
        float* ef_o = bi ? p.e_f0 : p.e_f1;

        stage_act<FAST, 0>(abuf, tid, r0, p.x_b + (long)t * CIN, (long)CW * CIN,
                           CIN, eb_i, CH);
        gru_compute<FAST>(abuf, r0, n0, lane, wave, p.Wih_qb, p.Whh_qb,
                          p.bih_q, p.bhh_q, ef_i, ef_o, eb_o);
        gbar_g(qb, slice, ++bk);
        stage_act<FAST, 1>(abuf, tid, r0, p.zflow + (size_t)bi * CB * CZ,
                           CZ, CZ, eb_o, CH);
        lin_compute<FAST>(abuf, r0, n0, lane, wave, CZ + CH, p.Wd_qb, p.bd_q, p.dvec_b);
        gbar_g(qb, slice, ++bk);
        phase_tail2<FAST, 0>(p, t, slab, slice, tid, lane, wave, Ra, Rs,
                             p.dvec_b, p.Wmu_qb, p.Wsg_qb, p.bmu_q, p.bsig_q);
        gbar_g(qb, slice, ++bk);
        if (t >= 2) {
            if (tid == 0) {
                while ((int)__hip_atomic_load(&p.pdone[slab * 16], __ATOMIC_RELAXED,
                                              __HIP_MEMORY_SCOPE_AGENT) < t - 1)
                    __builtin_amdgcn_s_sleep(2);
            }
            __syncthreads();
        }
        phase_flows2<FAST>(p, slab * 16 + slice * 2, tid, t, ZLp, PSp);
        gbar_g(qb, slice, ++bk);
        if (slice == 0 && tid == 0)
            __hip_atomic_store(&p.zbar[slab * 16], (u32)(t + 1),
                               __ATOMIC_RELAXED, __HIP_MEMORY_SCOPE_AGENT);
    }
}

template <bool FAST>
DEV void run_p(const Prm& p, int slab, int slice, int tid,
               bf16* abuf, float* Ra, float* Rs)
{
    const int lane = tid & 63, wave = tid >> 6;
    const int r0 = slab * 16, n0 = slice * 128;
    u32* pb = p.pbar + slab * 8 * 16;
    u32 bk = 0;
#pragma unroll 1
    for (int t = 0; t < CW; ++t) {
        if (tid == 0) {
            while (__hip_atomic_load(&p.zbar[slab * 16], __ATOMIC_RELAXED,
                                     __HIP_MEMORY_SCOPE_AGENT) < (u32)(t + 1))
                __builtin_amdgcn_s_sleep(2);
        }
        __syncthreads();

        const int bi = t & 1;
        const bf16*  db_i = bi ? p.d_b1 : p.d_b0;
        const float* df_i = bi ? p.d_f1 : p.d_f0;
        bf16*  db_o = bi ? p.d_b0 : p.d_b1;
        float* df_o = bi ? p.d_f0 : p.d_f1;

        stage_act<FAST, 2>(abuf, tid, r0, p.ztlg + (size_t)bi * CB * CZ,
                           CZ, CZ, db_i, CH);
        gru_compute<FAST>(abuf, r0, n0, lane, wave, p.Wih_pb, p.Whh_pb,
                          p.bih_p, p.bhh_p, df_i, df_o, db_o);
        gbar_g(pb, slice, ++bk);
        if (slice == 0 && tid == 0)
            __hip_atomic_store(&p.pdone[slab * 16], (u32)(t + 1),
                               __ATOMIC_RELAXED, __HIP_MEMORY_SCOPE_AGENT);
        stage_act<FAST, 0>(abuf, tid, r0, nullptr, 0, 0, db_o, CH);
        lin_compute<FAST>(abuf, r0, n0, lane, wave, CH, p.Wd_pb, p.bd_p, p.ddvec_b);
        gbar_g(pb, slice, ++bk);
        phase_tail2<FAST, 1>(p, t, slab, slice, tid, lane, wave, Ra, Rs,
                             p.ddvec_b, p.Wmu_pb, p.Wsg_pb, p.bmu_p, p.bsig_p);
    }
}

// ---------------------------------------------------------------------------
__launch_bounds__(512)
__global__ void mega(Prm p)
{
    extern __shared__ char smem[];
    bf16*  abuf = (bf16*)smem;
    float* Ra   = (float*)(smem + ABUF_BYTES);
    float* Rs   = Ra + REDN;
    float* ZLp  = (float*)(smem + ABUF_BYTES + RED2_BYTES);
    float* PSp  = ZLp + 2 * CZ;
    __shared__ int s_fast;

    const int wg = blockIdx.x, tid = threadIdx.x;
    const int gid = wg & 7, m = wg >> 3;          // m 0..31
    const bool isQ = gid < 4;
    const int slab = (isQ ? gid : gid - 4) * 4 + (m >> 3);   // 4 slabs per XCD
    const int slice = m & 7;

    // ---- startup: publish physical XCD id, verify nominal groups ----
    const u32 myx = (u32)__builtin_amdgcn_s_getreg(XCC_GETREG);
    if (tid == 0) {
        __hip_atomic_store(&p.xcc[wg * 16], myx, __ATOMIC_RELAXED, __HIP_MEMORY_SCOPE_AGENT);
        __hip_atomic_fetch_add(p.cnt, 1u, __ATOMIC_RELAXED, __HIP_MEMORY_SCOPE_AGENT);
        while (__hip_atomic_load(p.cnt, __ATOMIC_RELAXED, __HIP_MEMORY_SCOPE_AGENT) < 256u)
            __builtin_amdgcn_s_sleep(2);
    }
    __syncthreads();
    if (tid < 64) {
        bool eq = true;
        if (tid < 32) {
            u32 o = __hip_atomic_load(&p.xcc[(gid + 8 * tid) * 16],
                                      __ATOMIC_RELAXED, __HIP_MEMORY_SCOPE_AGENT);
            eq = (o == myx);
        }
        unsigned long long b = __ballot(eq);
        if (tid == 0) s_fast = (b == ~0ull) ? 1 : 0;
    }
    __syncthreads();
    const bool fast = (s_fast != 0);

    if (isQ) {
        if (fast) run_q<true>(p, slab, slice, tid, abuf, Ra, Rs, ZLp, PSp);
        else      run_q<false>(p, slab, slice, tid, abuf, Ra, Rs, ZLp, PSp);
    } else {
        if (fast) run_p<true>(p, slab, slice, tid, abuf, Ra, Rs);
        else      run_p<false>(p, slab, slice, tid, abuf, Ra, Rs);
    }
}

// ---------------------------------------------------------------------------
// Host driver
// ---------------------------------------------------------------------------
extern "C" void kernel_launch(void* const* d_in, const int* in_sizes, int n_in,
                              void* d_out, int out_size, void* d_ws, size_t ws_size,
                              hipStream_t stream)
{
    Prm p;
    const float* x      = (const float*)d_in[0];
    p.eps_q  = (const float*)d_in[1];
    p.eps_p  = (const float*)d_in[2];
    const float* Wih_q  = (const float*)d_in[3];
    const float* Whh_q  = (const float*)d_in[4];
    p.bih_q  = (const float*)d_in[5];
    p.bhh_q  = (const float*)d_in[6];
    const float* Wd_q   = (const float*)d_in[7];
    p.bd_q   = (const float*)d_in[8];
    const float* Wmu_q  = (const float*)d_in[9];
    p.bmu_q  = (const float*)d_in[10];
    const float* Wsig_q = (const float*)d_in[11];
    p.bsig_q = (const float*)d_in[12];
    p.Wp     = (const float*)d_in[13];
    p.bp     = (const float*)d_in[14];
    p.up     = (const float*)d_in[15];
    p.Wlg    = (const float*)d_in[16];
    p.blg    = (const float*)d_in[17];
    const float* Wih_p  = (const float*)d_in[18];
    const float* Whh_p  = (const float*)d_in[19];
    p.bih_p  = (const float*)d_in[20];
    p.bhh_p  = (const float*)d_in[21];
    const float* Wd_p   = (const float*)d_in[22];
    p.bd_p   = (const float*)d_in[23];
    const float* Wmu_p  = (const float*)d_in[24];
    p.bmu_p  = (const float*)d_in[25];
    const float* Wsig_p = (const float*)d_in[26];
    p.bsig_p = (const float*)d_in[27];

    p.out_o  = (float*)d_out;
    p.out_mu = p.out_o + (size_t)CB * CW * COUT;
    p.out_lv = p.out_mu + (size_t)CB * CW * CZ;

    char* wp_ = (char*)d_ws;
    auto carve = [&](size_t bytes) -> void* {
        void* q = (void*)wp_;
        wp_ += (bytes + 255) & ~(size_t)255;
        return q;
    };
    p.e_f0 = (float*)carve((size_t)CB * CH * 4);
    p.e_f1 = (float*)carve((size_t)CB * CH * 4);
    p.d_f0 = (float*)carve((size_t)CB * CH * 4);
    p.d_f1 = (float*)carve((size_t)CB * CH * 4);
    p.e_b0 = (bf16*)carve((size_t)CB * CH * 2);
    p.e_b1 = (bf16*)carve((size_t)CB * CH * 2);
    p.d_b0 = (bf16*)carve((size_t)CB * CH * 2);
    p.d_b1 = (bf16*)carve((size_t)CB * CH * 2);
    p.ztmp_f  = (float*)carve((size_t)CB * CZ * 4);
    p.dvec_b  = (bf16*)carve((size_t)CB * CD * 2);
    p.ddvec_b = (bf16*)carve((size_t)CB * CD * 2);
    p.zflow   = (bf16*)carve((size_t)2 * CB * CZ * 2);
    p.ztlg    = (bf16*)carve((size_t)2 * CB * CZ * 2);
    p.qbar    = (u32*)carve((size_t)16 * 8 * 16 * 4);
    p.pbar    = (u32*)carve((size_t)16 * 8 * 16 * 4);
    p.zbar    = (u32*)carve((size_t)16 * 16 * 4);
    p.pdone   = (u32*)carve((size_t)16 * 16 * 4);
    p.xcc     = (u32*)carve((size_t)256 * 16 * 4);
    p.cnt     = (u32*)carve(256);
    bf16* x_b    = (bf16*)carve((size_t)CB * CW * CIN * 2);
    bf16* Wih_qb = (bf16*)carve((size_t)3 * CH * CIN * 2);
    bf16* Whh_qb = (bf16*)carve((size_t)3 * CH * CH * 2);
    bf16* Wd_qb  = (bf16*)carve((size_t)CD * (CZ + CH) * 2);
    bf16* Wmu_qb = (bf16*)carve((size_t)CZ * CD * 2);
    bf16* Wsg_qb = (bf16*)carve((size_t)CZ * CD * 2);
    bf16* Wih_pb = (bf16*)carve((size_t)3 * CH * CZ * 2);
    bf16* Whh_pb = (bf16*)carve((size_t)3 * CH * CH * 2);
    bf16* Wd_pb  = (bf16*)carve((size_t)CD * CH * 2);
    bf16* Wmu_pb = (bf16*)carve((size_t)COUT * CD * 2);
    bf16* Wsg_pb = (bf16*)carve((size_t)COUT * CD * 2);
    p.x_b = x_b;       p.Wih_qb = Wih_qb; p.Whh_qb = Whh_qb;
    p.Wd_qb = Wd_qb;   p.Wmu_qb = Wmu_qb; p.Wsg_qb = Wsg_qb;
    p.Wih_pb = Wih_pb; p.Whh_pb = Whh_pb; p.Wd_pb = Wd_pb;
    p.Wmu_pb = Wmu_pb; p.Wsg_pb = Wsg_pb;

    hipMemsetAsync(p.e_f0, 0, (size_t)CB * CH * 4, stream);
    hipMemsetAsync(p.d_f0, 0, (size_t)CB * CH * 4, stream);
    hipMemsetAsync(p.e_b0, 0, (size_t)CB * CH * 2, stream);
    hipMemsetAsync(p.d_b0, 0, (size_t)CB * CH * 2, stream);
    hipMemsetAsync(p.zflow, 0, (size_t)CB * CZ * 2, stream);
    hipMemsetAsync(p.qbar, 0, (size_t)16 * 8 * 16 * 4, stream);
    hipMemsetAsync(p.pbar, 0, (size_t)16 * 8 * 16 * 4, stream);
    hipMemsetAsync(p.zbar, 0, (size_t)16 * 16 * 4, stream);
    hipMemsetAsync(p.pdone, 0, (size_t)16 * 16 * 4, stream);
    hipMemsetAsync(p.xcc, 0, (size_t)256 * 16 * 4, stream);
    hipMemsetAsync(p.cnt, 0, 256, stream);

    auto cvt = [&](const float* s, bf16* d, size_t n) {
        k_cvt<<<dim3((unsigned)((n / 4 + 255) / 256)), dim3(256), 0, stream>>>(s, d, (int)n);
    };
    cvt(x,      x_b,    (size_t)CB * CW * CIN);
    cvt(Wih_q,  Wih_qb, (size_t)3 * CH * CIN);
    cvt(Whh_q,  Whh_qb, (size_t)3 * CH * CH);
    cvt(Wd_q,   Wd_qb,  (size_t)CD * (CZ + CH));
    cvt(Wmu_q,  Wmu_qb, (size_t)CZ * CD);
    cvt(Wsig_q, Wsg_qb, (size_t)CZ * CD);
    cvt(Wih_p,  Wih_pb, (size_t)3 * CH * CZ);
    cvt(Whh_p,  Whh_pb, (size_t)3 * CH * CH);
    cvt(Wd_p,   Wd_pb,  (size_t)CD * CH);
    cvt(Wmu_p,  Wmu_pb, (size_t)COUT * CD);
    cvt(Wsig_p, Wsg_pb, (size_t)COUT * CD);

    mega<<<dim3(256), dim3(512), SMEM_BYTES, stream>>>(p);
}

// Round 18
// 7894.321 us; speedup vs baseline: 1.1603x; 1.0247x over previous
//
#include <hip/hip_runtime.h>

// ---------------------------------------------------------------------------
// OmniAnomaly forward, round 18: output-column XCD ownership -> L2-resident
// weights (~2.5MB/XCD), device-scope activation writes, cached unique-address
// history reads (r10-proven). Q = XCDs 0-3 (cols g*256..+256 of all Q mats),
// P = XCDs 4-7. 128-WG per-side barriers. Fallback (ws<400MB): depth-2 +
// device-scope reads (r17-class).
// B=256, W=128, IN=128, H=1024, Z=128, D=1024, OUT=128, K=3 flows
// ---------------------------------------------------------------------------

typedef __bf16 bf16;
typedef __bf16 bf16x8 __attribute__((ext_vector_type(8)));
typedef float  f32x4  __attribute__((ext_vector_type(4)));
typedef unsigned u32;

static constexpr int CB   = 256;
static constexpr int CW   = 128;
static constexpr int CIN  = 128;
static constexpr int CH   = 1024;
static constexpr int CZ   = 128;
static constexpr int CD   = 1024;
static constexpr int COUT = 128;

static constexpr int APITCH     = 1160;                      // 1152 + 8 pad
static constexpr int ABUF_BYTES = 16 * APITCH * 2;           // 37120
static constexpr int REDN       = 8 * 16 * 17;
static constexpr int RED2_BYTES = 2 * REDN * 4;              // 17408
static constexpr int FLOW_BYTES = (2 * CZ + 2 * 2 * CZ) * 4; // 3072
static constexpr int SMEM_BYTES = ABUF_BYTES + RED2_BYTES + FLOW_BYTES; // 57600

#define DEV static __device__ __forceinline__

DEV float sigmoidf_(float x) { return 1.0f / (1.0f + expf(-x)); }
DEV float softplusf_(float x) { return x > 20.0f ? x : log1pf(expf(x)); }
DEV bf16x8 ldfrag(const bf16* p) { return *reinterpret_cast<const bf16x8*>(p); }

#define MFMA(a, b, c) __builtin_amdgcn_mfma_f32_16x16x32_bf16((a), (b), (c), 0, 0, 0)

// device-coherent (sc0 sc1) accesses
DEV bf16x8 ldd16(const bf16* p) {
    bf16x8 v;
    asm volatile("global_load_dwordx4 %0, %1, off sc0 sc1\n\ts_waitcnt vmcnt(0)"
                 : "=v"(v) : "v"(p) : "memory");
    return v;
}
DEV bf16x8 ldd16_nw(const bf16* p) {
    bf16x8 v;
    asm volatile("global_load_dwordx4 %0, %1, off sc0 sc1"
                 : "=v"(v) : "v"(p) : "memory");
    return v;
}
DEV u32 ldd4(const void* p) {
    u32 v;
    asm volatile("global_load_dword %0, %1, off sc0 sc1\n\ts_waitcnt vmcnt(0)"
                 : "=v"(v) : "v"(p) : "memory");
    return v;
}
DEV void std4(void* p, u32 v) {
    asm volatile("global_store_dword %0, %1, off sc0 sc1" :: "v"(p), "v"(v) : "memory");
}
DEV void vm_wait0() {
    asm volatile("s_waitcnt vmcnt(0)" ::: "memory");
    __builtin_amdgcn_sched_barrier(0);
}
DEV u32 pk2(float a, float b) {
    union { bf16 h[2]; u32 u; } r;
    r.h[0] = (bf16)a; r.h[1] = (bf16)b;
    return r.u;
}

struct Prm {
    const float *eps_q, *eps_p;
    const float *bih_q, *bhh_q, *bd_q, *bmu_q, *bsig_q;
    const float *Wp, *bp, *up, *Wlg, *blg;
    const float *bih_p, *bhh_p, *bd_p, *bmu_p, *bsig_p;
    const bf16 *x_b, *Wih_qb, *Whh_qb, *Wd_qb, *Wmu_qb, *Wsg_qb;
    const bf16 *Wih_pb, *Whh_pb, *Wd_pb, *Wmu_pb, *Wsg_pb;
    float *e_f0, *e_f1, *d_f0, *d_f1;   // fp32 masters (WG-private patches)
    bf16 *e_h, *d_h;        // [(BIG?CW+1:2)][CB][CH]
    bf16 *dvec_h, *ddvec_h; // [(BIG?CW:1)][CB][CD]
    float *ztmp_h;          // [(BIG?CW:1)][CB][CZ]
    bf16 *zflow_h;          // [(BIG?CW+1:2)][CB][CZ]
    bf16 *ztlg_h;           // [(BIG?CW:2)][CB][CZ]
    u32 *qbar, *pbar, *zbar, *pdone;    // 128-flag arrays (16-u32 spacing)
    float *out_o, *out_mu, *out_lv;
};

// 128-WG per-side barrier (r8-proven): each of 512 threads' first 128 poll.
DEV void gbar128(u32* flg, int lwg, u32 k)
{
    asm volatile("s_waitcnt vmcnt(0)" ::: "memory");
    __syncthreads();
    if (threadIdx.x == 0)
        __hip_atomic_store(&flg[lwg * 16], k, __ATOMIC_RELAXED, __HIP_MEMORY_SCOPE_AGENT);
    if (threadIdx.x < 128) {
        while (__hip_atomic_load(&flg[threadIdx.x * 16], __ATOMIC_RELAXED,
                                 __HIP_MEMORY_SCOPE_AGENT) < k)
            __builtin_amdgcn_s_sleep(1);
    }
    __syncthreads();
}

// ---------------------------------------------------------------------------
__global__ void k_cvt(const float* __restrict__ src, bf16* __restrict__ dst, int n)
{
    int i = (blockIdx.x * blockDim.x + threadIdx.x) * 4;
    if (i < n) {
        float4 v = *reinterpret_cast<const float4*>(src + i);
        *reinterpret_cast<u32*>(dst + i)     = pk2(v.x, v.y);
        *reinterpret_cast<u32*>(dst + i + 2) = pk2(v.z, v.w);
    }
}

// ---------------------------------------------------------------------------
// Stage slab rows [r0,+16) x [head(K1) | body(1024)] into abuf.
// BIG: plain cached loads (unique addresses). FB: batched sc0sc1.
// HM: 0 = always-cached head (x_b), 1 = data head (mode-dependent).
// ---------------------------------------------------------------------------
template <bool BIG, int HM>
DEV void stage_act(bf16* abuf, int tid, int r0,
                   const bf16* head, long hs, int K1,
                   const bf16* body, long bs)
{
    if constexpr (BIG) {
        for (int j = 0; j < 4; ++j) {
            const int idx = tid + j * 512;
            const int row = idx >> 7;
            const int k = (idx & 127) * 8;
            *reinterpret_cast<bf16x8*>(abuf + (long)row * APITCH + K1 + k) =
                ldfrag(body + (long)(r0 + row) * bs + k);
        }
    } else {
        bf16x8 v[4];
        long dst[4];
#pragma unroll
        for (int j = 0; j < 4; ++j) {
            const int idx = tid + j * 512;
            const int row = idx >> 7;
            const int k = (idx & 127) * 8;
            v[j] = ldd16_nw(body + (long)(r0 + row) * bs + k);
            dst[j] = (long)row * APITCH + K1 + k;
        }
        vm_wait0();
#pragma unroll
        for (int j = 0; j < 4; ++j)
            *reinterpret_cast<bf16x8*>(abuf + dst[j]) = v[j];
    }
    if (K1 > 0) {
        const int HC = K1 >> 3;
        for (int idx = tid; idx < 16 * HC; idx += 512) {
            const int row = idx / HC;
            const int k = (idx - row * HC) * 8;
            const bf16* s = head + (long)(r0 + row) * hs + k;
            bf16x8 hv;
            if constexpr (HM == 0) hv = ldfrag(s);
            else                   hv = BIG ? ldfrag(s) : ldd16(s);
            *reinterpret_cast<bf16x8*>(abuf + (long)row * APITCH + k) = hv;
        }
    }
    __syncthreads();
}

// ---------------------------------------------------------------------------
// GRU compute (r17 prefetch version; weights plain cached -> L2-resident).
// ---------------------------------------------------------------------------
DEV void gru_compute(const bf16* abuf, int r0, int n0, int lane, int wave,
                     const bf16* __restrict__ Wih, const bf16* __restrict__ Whh,
                     const float* __restrict__ bih, const float* __restrict__ bhh,
                     const float* __restrict__ Efin,
                     float* __restrict__ Efo, bf16* __restrict__ Ebo)
{
    const int lr = lane & 15, lkE = (lane >> 4) * 8;
    const int c = n0 + wave * 16 + lr;
    const bf16* arow = abuf + (long)lr * APITCH;

    f32x4 acc[4] = {};
    {
        bf16x8 wv[4][3];
#pragma unroll
        for (int j = 0; j < 4; ++j)
#pragma unroll
            for (int g = 0; g < 3; ++g)
                wv[j][g] = ldfrag(Wih + ((long)g * CH + c) * CIN + j * 32 + lkE);
#pragma unroll
        for (int j = 0; j < 4; ++j) {
            bf16x8 a = *reinterpret_cast<const bf16x8*>(arow + j * 32 + lkE);
            acc[0] = MFMA(a, wv[j][0], acc[0]);
            acc[1] = MFMA(a, wv[j][1], acc[1]);
            acc[2] = MFMA(a, wv[j][2], acc[2]);
        }
    }
    {
        const bf16* wp0 = Whh + ((long)0 * CH + c) * CH + lkE;
        const bf16* wp1 = Whh + ((long)1 * CH + c) * CH + lkE;
        const bf16* wp2 = Whh + ((long)2 * CH + c) * CH + lkE;
        bf16x8 wv[4][3];
#pragma unroll
        for (int j = 0; j < 4; ++j) {
            wv[j][0] = ldfrag(wp0 + j * 32);
            wv[j][1] = ldfrag(wp1 + j * 32);
            wv[j][2] = ldfrag(wp2 + j * 32);
        }
#pragma unroll
        for (int kb = 0; kb < 32; ++kb) {
            const int sl = kb & 3;
            bf16x8 a = *reinterpret_cast<const bf16x8*>(arow + CIN + kb * 32 + lkE);
            acc[0] = MFMA(a, wv[sl][0], acc[0]);
            acc[1] = MFMA(a, wv[sl][1], acc[1]);
            acc[3] = MFMA(a, wv[sl][2], acc[3]);
            if (kb < 28) {
                wv[sl][0] = ldfrag(wp0 + (kb + 4) * 32);
                wv[sl][1] = ldfrag(wp1 + (kb + 4) * 32);
                wv[sl][2] = ldfrag(wp2 + (kb + 4) * 32);
            }
        }
    }

    const float b0r = bih[c] + bhh[c];
    const float b0z = bih[CH + c] + bhh[CH + c];
    const float bin = bih[2 * CH + c];
    const float bhn = bhh[2 * CH + c];
    const int rbase = r0 + (lane >> 4) * 4;
#pragma unroll
    for (int i = 0; i < 4; ++i) {
        const int row = rbase + i;
        float r = sigmoidf_(acc[0][i] + b0r);
        float u = sigmoidf_(acc[1][i] + b0z);
        float n = tanhf(acc[2][i] + bin + r * (acc[3][i] + bhn));
        float en = (1.0f - u) * n + u * Efin[(long)row * CH + c];
        Efo[(long)row * CH + c] = en;
        float vB = __shfl_xor(en, 1);
        if (!(lane & 1))
            std4(Ebo + (long)row * CH + c, pk2(en, vB));
    }
}

// ---------------------------------------------------------------------------
DEV void lin_compute(const bf16* abuf, int r0, int n0, int lane, int wave, int Ktot,
                     const bf16* __restrict__ W,
                     const float* __restrict__ bias, bf16* __restrict__ Out)
{
    const int lr = lane & 15, lkE = (lane >> 4) * 8;
    const int c = n0 + wave * 16 + lr;
    const bf16* arow = abuf + (long)lr * APITCH;
    const bf16* wrow = W + (long)c * Ktot;
    const int kofs = Ktot - CH;

    f32x4 acc = {};
    {
        const bf16* wp = wrow + kofs + lkE;
        bf16x8 wv[8];
#pragma unroll
        for (int j = 0; j < 8; ++j) wv[j] = ldfrag(wp + j * 32);
#pragma unroll
        for (int kb = 0; kb < 32; ++kb) {
            const int sl = kb & 7;
            bf16x8 a = *reinterpret_cast<const bf16x8*>(arow + kofs + kb * 32 + lkE);
            acc = MFMA(a, wv[sl], acc);
            if (kb < 24) wv[sl] = ldfrag(wp + (kb + 8) * 32);
        }
    }
    if (Ktot > CH) {
        bf16x8 wv[4];
#pragma unroll
        for (int j = 0; j < 4; ++j) wv[j] = ldfrag(wrow + j * 32 + lkE);
#pragma unroll
        for (int j = 0; j < 4; ++j) {
            bf16x8 a = *reinterpret_cast<const bf16x8*>(arow + j * 32 + lkE);
            acc = MFMA(a, wv[j], acc);
        }
    }

    const float bb = bias[c];
    const int rbase = r0 + (lane >> 4) * 4;
#pragma unroll
    for (int i = 0; i < 4; ++i) {
        float v = acc[i] + bb;
        float vB = __shfl_xor(v, 1);
        if (!(lane & 1))
            std4(Out + (long)(rbase + i) * CD + c, pk2(v, vB));
    }
}

// ---------------------------------------------------------------------------
// Two-head tail: rows [mb,+16) x cols [nb,+16), 8-wave K-split, LDS reduce.
// ---------------------------------------------------------------------------
template <bool BIG, int MODE>
DEV void phase_tail2(const Prm& p, int t, int mb, int nb, int tid,
                     int lane, int wave, float* Ra, float* Rs,
                     const bf16* __restrict__ A, float* __restrict__ ztmp,
                     const bf16* __restrict__ Wa, const bf16* __restrict__ Wb,
                     const float* __restrict__ ba, const float* __restrict__ bb)
{
    const int lr = lane & 15, lkE = (lane >> 4) * 8;
    f32x4 am = {}, as = {};
    const int k0 = wave * 128;
    bf16x8 av[4], bmv[4], bsv[4];
#pragma unroll
    for (int j = 0; j < 4; ++j) {
        const int k = k0 + j * 32;
        const bf16* ap = A + (long)(mb + lr) * CD + k + lkE;
        av[j]  = BIG ? ldfrag(ap) : ldd16_nw(ap);
        bmv[j] = ldfrag(Wa + (long)(nb + lr) * CD + k + lkE);
        bsv[j] = ldfrag(Wb + (long)(nb + lr) * CD + k + lkE);
    }
    if constexpr (!BIG) vm_wait0();
#pragma unroll
    for (int j = 0; j < 4; ++j) {
        am = MFMA(av[j], bmv[j], am);
        as = MFMA(av[j], bsv[j], as);
    }
    __syncthreads();
#pragma unroll
    for (int i = 0; i < 4; ++i) {
        Ra[(wave * 16 + (lane >> 4) * 4 + i) * 17 + lr] = am[i];
        Rs[(wave * 16 + (lane >> 4) * 4 + i) * 17 + lr] = as[i];
    }
    __syncthreads();
    if (tid < 256) {
        const int trow = tid >> 4, tcol = tid & 15;
        float vm = 0.f, vs = 0.f;
#pragma unroll
        for (int w = 0; w < 8; ++w) {
            vm += Ra[(w * 16 + trow) * 17 + tcol];
            vs += Rs[(w * 16 + trow) * 17 + tcol];
        }
        const int row = mb + trow, col = nb + tcol;
        if constexpr (MODE == 0) {
            float mu = vm + ba[col];
            float lv = softplusf_(vs + bb[col]);
            float e  = p.eps_q[(long)row * CW * CZ + (long)t * CZ + col];
            float z  = mu + expf(0.5f * lv) * e;
            p.out_mu[(long)row * CW * CZ + (long)t * CZ + col] = mu;
            p.out_lv[(long)row * CW * CZ + (long)t * CZ + col] = lv;
            std4(ztmp + (long)row * CZ + col, __float_as_uint(z));
        } else {
            float m  = vm + ba[col];
            float sg = softplusf_(vs + bb[col]);
            float e  = p.eps_p[(long)row * CW * COUT + (long)t * COUT + col];
            p.out_o[(long)row * CW * COUT + (long)t * COUT + col] = m + sg * e;
        }
    }
}

// ---------------------------------------------------------------------------
// Planar flows + LGSSM: 2 rows/WG.
// ---------------------------------------------------------------------------
template <bool BIG>
DEV void phase_flows2(const Prm& p, int rowbase, int tid, int t, float* zl, float* ps,
                      const float* __restrict__ ztmp,
                      bf16* __restrict__ ztlg, bf16* __restrict__ zflow_next)
{
    const int rg = tid >> 8;
    const int sub = tid & 255;
    const int c = sub & 127, half = sub >> 7;
    const int row = rowbase + rg;
    float* zrow = zl + rg * CZ;
    float* pall = ps + rg * 2 * CZ;

    if (half == 0)
        zrow[c] = BIG ? ztmp[(long)row * CZ + c]
                      : __uint_as_float(ldd4(ztmp + (long)row * CZ + c));
    __syncthreads();

#pragma unroll 1
    for (int kf = 0; kf < 3; ++kf) {
        const float* wr = p.Wp + ((long)kf * CZ + c) * CZ + half * 64;
        const float* zh = zrow + half * 64;
        float s = 0.f;
#pragma unroll
        for (int j = 0; j < 64; j += 4) {
            float4 w = *reinterpret_cast<const float4*>(wr + j);
            s += zh[j] * w.x + zh[j + 1] * w.y + zh[j + 2] * w.z + zh[j + 3] * w.w;
        }
        pall[half * CZ + c] = s;
        __syncthreads();
        if (half == 0) {
            float sf = pall[c] + pall[CZ + c] + p.bp[kf * CZ + c];
            zrow[c] += p.up[kf] * tanhf(sf);
        }
        __syncthreads();
    }
    {
        const float* wr = p.Wlg + (long)c * CZ + half * 64;
        const float* zh = zrow + half * 64;
        float s = 0.f;
#pragma unroll
        for (int j = 0; j < 64; j += 4) {
            float4 w = *reinterpret_cast<const float4*>(wr + j);
            s += zh[j] * w.x + zh[j + 1] * w.y + zh[j + 2] * w.z + zh[j + 3] * w.w;
        }
        pall[half * CZ + c] = s;
        __syncthreads();
        if (half == 0) {
            float zt = pall[c] + pall[CZ + c] + p.blg[c];
            float ztB = __shfl_xor(zt, 1);
            if (!(c & 1)) {
                std4(ztlg + (long)row * CZ + c, pk2(zt, ztB));
                std4(zflow_next + (long)row * CZ + c, pk2(zrow[c], zrow[c + 1]));
            }
        }
    }
}

// ---------------------------------------------------------------------------
template <bool BIG>
DEV void run_q(const Prm& p, int lwg, int tid,
               bf16* abuf, float* Ra, float* Rs, float* ZLp, float* PSp)
{
    const int lane = tid & 63, wave = tid >> 6;
    const int g = lwg >> 5, m = lwg & 31;
    const int r0 = (m >> 1) * 16;
    const int n0 = g * 256 + (m & 1) * 128;
    const int nt = g * 32 + (m & 1) * 16;
    const size_t SH = (size_t)CB * CH, SD = (size_t)CB * CD, SZ = (size_t)CB * CZ;
    u32 bk = 0;
#pragma unroll 1
    for (int t = 0; t < CW; ++t) {
        const int eIn  = BIG ? t : (t & 1);
        const int eOut = BIG ? (t + 1) : ((t + 1) & 1);
        const int dT   = BIG ? t : 0;
        const int zT   = BIG ? t : (t & 1);
        const float* ef_i = (t & 1) ? p.e_f1 : p.e_f0;
        float*       ef_o = (t & 1) ? p.e_f0 : p.e_f1;

        stage_act<BIG, 0>(abuf, tid, r0, p.x_b + (long)t * CIN, (long)CW * CIN,
                          CIN, p.e_h + (size_t)eIn * SH, CH);
        gru_compute(abuf, r0, n0, lane, wave, p.Wih_qb, p.Whh_qb,
                    p.bih_q, p.bhh_q, ef_i, ef_o, p.e_h + (size_t)eOut * SH);
        gbar128(p.qbar, lwg, ++bk);

        stage_act<BIG, 1>(abuf, tid, r0, p.zflow_h + (size_t)eIn * SZ, CZ, CZ,
                          p.e_h + (size_t)eOut * SH, CH);
        lin_compute(abuf, r0, n0, lane, wave, CZ + CH, p.Wd_qb, p.bd_q,
                    p.dvec_h + (size_t)dT * SD);
        gbar128(p.qbar, lwg, ++bk);

        phase_tail2<BIG, 0>(p, t, r0, nt, tid, lane, wave, Ra, Rs,
                            p.dvec_h + (size_t)dT * SD, p.ztmp_h + (size_t)dT * SZ,
                            p.Wmu_qb, p.Wsg_qb, p.bmu_q, p.bsig_q);
        gbar128(p.qbar, lwg, ++bk);

        if constexpr (!BIG) {
            if (t >= 2) {
                if (tid < 128) {
                    while ((int)__hip_atomic_load(&p.pdone[tid * 16], __ATOMIC_RELAXED,
                                                  __HIP_MEMORY_SCOPE_AGENT) < t - 1)
                        __builtin_amdgcn_s_sleep(2);
                }
                __syncthreads();
            }
        }
        phase_flows2<BIG>(p, lwg * 2, tid, t, ZLp, PSp,
                          p.ztmp_h + (size_t)dT * SZ,
                          p.ztlg_h + (size_t)zT * SZ,
                          p.zflow_h + (size_t)eOut * SZ);
        asm volatile("s_waitcnt vmcnt(0)" ::: "memory");
        __syncthreads();
        if (tid == 0)
            __hip_atomic_store(&p.zbar[lwg * 16], (u32)(t + 1),
                               __ATOMIC_RELAXED, __HIP_MEMORY_SCOPE_AGENT);
        __syncthreads();
    }
}

template <bool BIG>
DEV void run_p(const Prm& p, int lwg, int tid,
               bf16* abuf, float* Ra, float* Rs)
{
    const int lane = tid & 63, wave = tid >> 6;
    const int g = lwg >> 5, m = lwg & 31;
    const int r0 = (m >> 1) * 16;
    const int n0 = g * 256 + (m & 1) * 128;
    const int nt = g * 32 + (m & 1) * 16;
    const size_t SH = (size_t)CB * CH, SD = (size_t)CB * CD, SZ = (size_t)CB * CZ;
    u32 bk = 0;
#pragma unroll 1
    for (int t = 0; t < CW; ++t) {
        if (tid < 128) {
            while (__hip_atomic_load(&p.zbar[tid * 16], __ATOMIC_RELAXED,
                                     __HIP_MEMORY_SCOPE_AGENT) < (u32)(t + 1))
                __builtin_amdgcn_s_sleep(2);
        }
        __syncthreads();

        const int sIn  = BIG ? t : (t & 1);
        const int sOut = BIG ? (t + 1) : ((t + 1) & 1);
        const int dT   = BIG ? t : 0;
        const int zT   = BIG ? t : (t & 1);
        const float* df_i = (t & 1) ? p.d_f1 : p.d_f0;
        float*       df_o = (t & 1) ? p.d_f0 : p.d_f1;

        stage_act<BIG, 1>(abuf, tid, r0, p.ztlg_h + (size_t)zT * SZ, CZ, CZ,
                          p.d_h + (size_t)sIn * SH, CH);
        gru_compute(abuf, r0, n0, lane, wave, p.Wih_pb, p.Whh_pb,
                    p.bih_p, p.bhh_p, df_i, df_o, p.d_h + (size_t)sOut * SH);
        gbar128(p.pbar, lwg, ++bk);
        if constexpr (!BIG) {
            if (tid == 0)
                __hip_atomic_store(&p.pdone[lwg * 16], (u32)(t + 1),
                                   __ATOMIC_RELAXED, __HIP_MEMORY_SCOPE_AGENT);
        }

        stage_act<BIG, 0>(abuf, tid, r0, nullptr, 0, 0,
                          p.d_h + (size_t)sOut * SH, CH);
        lin_compute(abuf, r0, n0, lane, wave, CH, p.Wd_pb, p.bd_p,
                    p.ddvec_h + (size_t)dT * SD);
        gbar128(p.pbar, lwg, ++bk);

        phase_tail2<BIG, 1>(p, t, r0, nt, tid, lane, wave, Ra, Rs,
                            p.ddvec_h + (size_t)dT * SD, nullptr,
                            p.Wmu_pb, p.Wsg_pb, p.bmu_p, p.bsig_p);
        // ddvec reuse (FB) protected by next barP after GRU(t+1)
    }
}

// ---------------------------------------------------------------------------
template <bool BIG>
__launch_bounds__(512)
__global__ void mega(Prm p)
{
    extern __shared__ char smem[];
    bf16*  abuf = (bf16*)smem;
    float* Ra   = (float*)(smem + ABUF_BYTES);
    float* Rs   = Ra + REDN;
    float* ZLp  = (float*)(smem + ABUF_BYTES + RED2_BYTES);
    float* PSp  = ZLp + 2 * CZ;

    const int wg = blockIdx.x, tid = threadIdx.x;
    const int gid = wg & 7, m = wg >> 3;          // m 0..31
    const bool isQ = gid < 4;
    const int lwg = (isQ ? gid : gid - 4) * 32 + m;   // 0..127 per side

    if (isQ) run_q<BIG>(p, lwg, tid, abuf, Ra, Rs, ZLp, PSp);
    else     run_p<BIG>(p, lwg, tid, abuf, Ra, Rs);
}

// ---------------------------------------------------------------------------
// Host driver
// ---------------------------------------------------------------------------
extern "C" void kernel_launch(void* const* d_in, const int* in_sizes, int n_in,
                              void* d_out, int out_size, void* d_ws, size_t ws_size,
                              hipStream_t stream)
{
    Prm p;
    const float* x      = (const float*)d_in[0];
    p.eps_q  = (const float*)d_in[1];
    p.eps_p  = (const float*)d_in[2];
    const float* Wih_q  = (const float*)d_in[3];
    const float* Whh_q  = (const float*)d_in[4];
    p.bih_q  = (const float*)d_in[5];
    p.bhh_q  = (const float*)d_in[6];
    const float* Wd_q   = (const float*)d_in[7];
    p.bd_q   = (const float*)d_in[8];
    const float* Wmu_q  = (const float*)d_in[9];
    p.bmu_q  = (const float*)d_in[10];
    const float* Wsig_q = (const float*)d_in[11];
    p.bsig_q = (const float*)d_in[12];
    p.Wp     = (const float*)d_in[13];
    p.bp     = (const float*)d_in[14];
    p.up     = (const float*)d_in[15];
    p.Wlg    = (const float*)d_in[16];
    p.blg    = (const float*)d_in[17];
    const float* Wih_p  = (const float*)d_in[18];
    const float* Whh_p  = (const float*)d_in[19];
    p.bih_p  = (const float*)d_in[20];
    p.bhh_p  = (const float*)d_in[21];
    const float* Wd_p   = (const float*)d_in[22];
    p.bd_p   = (const float*)d_in[23];
    const float* Wmu_p  = (const float*)d_in[24];
    p.bmu_p  = (const float*)d_in[25];
    const float* Wsig_p = (const float*)d_in[26];
    p.bsig_p = (const float*)d_in[27];

    p.out_o  = (float*)d_out;
    p.out_mu = p.out_o + (size_t)CB * CW * COUT;
    p.out_lv = p.out_mu + (size_t)CB * CW * CZ;

    const bool BIGM = ws_size >= (size_t)400 * 1024 * 1024;
    const int NS = BIGM ? (CW + 1) : 2;
    const int NT = BIGM ? CW : 1;
    const int NZ = BIGM ? CW : 2;

    char* wp_ = (char*)d_ws;
    auto carve = [&](size_t bytes) -> void* {
        void* q = (void*)wp_;
        wp_ += (bytes + 255) & ~(size_t)255;
        return q;
    };
    p.e_f0 = (float*)carve((size_t)CB * CH * 4);
    p.e_f1 = (float*)carve((size_t)CB * CH * 4);
    p.d_f0 = (float*)carve((size_t)CB * CH * 4);
    p.d_f1 = (float*)carve((size_t)CB * CH * 4);
    p.e_h     = (bf16*)carve((size_t)NS * CB * CH * 2);
    p.d_h     = (bf16*)carve((size_t)NS * CB * CH * 2);
    p.dvec_h  = (bf16*)carve((size_t)NT * CB * CD * 2);
    p.ddvec_h = (bf16*)carve((size_t)NT * CB * CD * 2);
    p.ztmp_h  = (float*)carve((size_t)NT * CB * CZ * 4);
    p.zflow_h = (bf16*)carve((size_t)NS * CB * CZ * 2);
    p.ztlg_h  = (bf16*)carve((size_t)NZ * CB * CZ * 2);
    p.qbar    = (u32*)carve((size_t)128 * 16 * 4);
    p.pbar    = (u32*)carve((size_t)128 * 16 * 4);
    p.zbar    = (u32*)carve((size_t)128 * 16 * 4);
    p.pdone   = (u32*)carve((size_t)128 * 16 * 4);
    bf16* x_b    = (bf16*)carve((size_t)CB * CW * CIN * 2);
    bf16* Wih_qb = (bf16*)carve((size_t)3 * CH * CIN * 2);
    bf16* Whh_qb = (bf16*)carve((size_t)3 * CH * CH * 2);
    bf16* Wd_qb  = (bf16*)carve((size_t)CD * (CZ + CH) * 2);
    bf16* Wmu_qb = (bf16*)carve((size_t)CZ * CD * 2);
    bf16* Wsg_qb = (bf16*)carve((size_t)CZ * CD * 2);
    bf16* Wih_pb = (bf16*)carve((size_t)3 * CH * CZ * 2);
    bf16* Whh_pb = (bf16*)carve((size_t)3 * CH * CH * 2);
    bf16* Wd_pb  = (bf16*)carve((size_t)CD * CH * 2);
    bf16* Wmu_pb = (bf16*)carve((size_t)COUT * CD * 2);
    bf16* Wsg_pb = (bf16*)carve((size_t)COUT * CD * 2);
    p.x_b = x_b;       p.Wih_qb = Wih_qb; p.Whh_qb = Whh_qb;
    p.Wd_qb = Wd_qb;   p.Wmu_qb = Wmu_qb; p.Wsg_qb = Wsg_qb;
    p.Wih_pb = Wih_pb; p.Whh_pb = Whh_pb; p.Wd_pb = Wd_pb;
    p.Wmu_pb = Wmu_pb; p.Wsg_pb = Wsg_pb;

    hipMemsetAsync(p.e_f0, 0, (size_t)CB * CH * 4, stream);
    hipMemsetAsync(p.d_f0, 0, (size_t)CB * CH * 4, stream);
    hipMemsetAsync(p.e_h, 0, (size_t)CB * CH * 2, stream);      // slot 0
    hipMemsetAsync(p.d_h, 0, (size_t)CB * CH * 2, stream);
    hipMemsetAsync(p.zflow_h, 0, (size_t)CB * CZ * 2, stream);  // slot 0
    hipMemsetAsync(p.qbar, 0, (size_t)128 * 16 * 4, stream);
    hipMemsetAsync(p.pbar, 0, (size_t)128 * 16 * 4, stream);
    hipMemsetAsync(p.zbar, 0, (size_t)128 * 16 * 4, stream);
    hipMemsetAsync(p.pdone, 0, (size_t)128 * 16 * 4, stream);

    auto cvt = [&](const float* s, bf16* d, size_t n) {
        k_cvt<<<dim3((unsigned)((n / 4 + 255) / 256)), dim3(256), 0, stream>>>(s, d, (int)n);
    };
    cvt(x,      x_b,    (size_t)CB * CW * CIN);
    cvt(Wih_q,  Wih_qb, (size_t)3 * CH * CIN);
    cvt(Whh_q,  Whh_qb, (size_t)3 * CH * CH);
    cvt(Wd_q,   Wd_qb,  (size_t)CD * (CZ + CH));
    cvt(Wmu_q,  Wmu_qb, (size_t)CZ * CD);
    cvt(Wsig_q, Wsg_qb, (size_t)CZ * CD);
    cvt(Wih_p,  Wih_pb, (size_t)3 * CH * CZ);
    cvt(Whh_p,  Whh_pb, (size_t)3 * CH * CH);
    cvt(Wd_p,   Wd_pb,  (size_t)CD * CH);
    cvt(Wmu_p,  Wmu_pb, (size_t)COUT * CD);
    cvt(Wsig_p, Wsg_pb, (size_t)COUT * CD);

    if (BIGM)
        mega<true><<<dim3(256), dim3(512), SMEM_BYTES, stream>>>(p);
    else
        mega<false><<<dim3(256), dim3(512), SMEM_BYTES, stream>>>(p);
}